// Round 17
// baseline (1760.026 us; speedup 1.0000x reference)
//
#include <hip/hip_runtime.h>
#include <cmath>

// Problem constants
#define Bb   64
#define Tt   128
#define Dd   2048
#define Hh   512
#define Gg   2048      // 4*H
#define Cc   101
#define PC   112       // classes padded to 7*16 for MFMA
#define ROWS 8192      // B*T

typedef unsigned short u16;
typedef __attribute__((ext_vector_type(8))) short bf16x8;
typedef __attribute__((ext_vector_type(4))) float f32x4;

// LDS row padding: 42 u16 = 21 dwords (ODD -> bank stride coprime with 32;
// frag reads max 2-way = free). 40/136 (even dwords) measured 8-way:
// gemm1 SQ_LDS_BANK_CONFLICT 3.4e7/dispatch ~ 22% of its cycles.
#define PAD32 42
#define PAD128 138

// ---------------- bf16 hi/lo split helpers ----------------
__device__ __forceinline__ u16 bf16rne(float x) {
  unsigned u = __float_as_uint(x);
  unsigned r = (u + 0x7fffu + ((u >> 16) & 1u)) >> 16;
  return (u16)r;
}
__device__ __forceinline__ void split_bf16(float x, u16& h, u16& l) {
  h = bf16rne(x);
  l = bf16rne(x - __uint_as_float(((unsigned)h) << 16));
}
__device__ __forceinline__ float sigm(float x) { return 1.f / (1.f + expf(-x)); }

// X [ROWS x Dd] fp32 -> Xhi, Xlo bf16 (same layout)
__global__ __launch_bounds__(256)
void convert_hilo(const float* __restrict__ src, u16* __restrict__ hi,
                  u16* __restrict__ lo, int n4) {
  for (int i = blockIdx.x * 256 + threadIdx.x; i < n4; i += gridDim.x * 256) {
    const float4 v = ((const float4*)src)[i];
    ushort4 h, l;
    split_bf16(v.x, h.x, l.x);
    split_bf16(v.y, h.y, l.y);
    split_bf16(v.z, h.z, l.z);
    split_bf16(v.w, h.w, l.w);
    ((ushort4*)hi)[i] = h;
    ((ushort4*)lo)[i] = l;
  }
}

// W1 top [Dd x Gg] -> W1T hi/lo [Gg x Dd] bf16  (for gemm1 B operand)
__global__ __launch_bounds__(256)
void convertT_w1(const float* __restrict__ W1, u16* __restrict__ Th,
                 u16* __restrict__ Tl) {
  __shared__ float tl[32][33];
  const int tx = threadIdx.x, ty = threadIdx.y;   // 32, 8
  const int k0 = blockIdx.x * 32, c0 = blockIdx.y * 32;
#pragma unroll
  for (int j = 0; j < 4; ++j)
    tl[ty + j * 8][tx] = W1[(size_t)(k0 + ty + j * 8) * Gg + (c0 + tx)];
  __syncthreads();
#pragma unroll
  for (int j = 0; j < 4; ++j) {
    const float v = tl[tx][ty + j * 8];
    u16 h, l;
    split_bf16(v, h, l);
    const size_t o = (size_t)(c0 + ty + j * 8) * Dd + (k0 + tx);
    Th[o] = h;
    Tl[o] = l;
  }
}

// Wout [Hh x Cc] -> WoutT hi/lo [PC x Hh] (rows >= Cc zero)
__global__ __launch_bounds__(256)
void convert_woutT(const float* __restrict__ Wout, u16* __restrict__ Th,
                   u16* __restrict__ Tl) {
  const int c = blockIdx.x;
  for (int k = threadIdx.x; k < Hh; k += 256) {
    const float v = (c < Cc) ? Wout[k * Cc + c] : 0.f;
    u16 h, l;
    split_bf16(v, h, l);
    Th[c * Hh + k] = h;
    Tl[c * Hh + k] = l;
  }
}

// Recurrent weights, permuted + split:
// WP[cg 128][vc 16][K], vc = g*4 + m for col = g*512 + cg*4 + m.
__global__ __launch_bounds__(256)
void permuteW(const float* __restrict__ src, u16* __restrict__ dh,
              u16* __restrict__ dl, int K) {
  __shared__ float tl[32][33];
  const int tx = threadIdx.x, ty = threadIdx.y;   // 32, 8
  const int k0 = blockIdx.x * 32, c0 = blockIdx.y * 32;
#pragma unroll
  for (int j = 0; j < 4; ++j)
    tl[ty + j * 8][tx] = src[(size_t)(k0 + ty + j * 8) * Gg + (c0 + tx)];
  __syncthreads();
#pragma unroll
  for (int j = 0; j < 4; ++j) {
    const int col = c0 + ty + j * 8;
    const int g = col >> 9, mg = col & 511;
    const int cg = mg >> 2, m = mg & 3;
    const float v = tl[tx][ty + j * 8];
    u16 h, l;
    split_bf16(v, h, l);
    const size_t o = (size_t)(cg * 16 + g * 4 + m) * K + k0 + tx;
    dh[o] = h;
    dl[o] = l;
  }
}

// ---------------- MFMA bf16x3 GEMM: pre = X @ W1 + b1 ----------------
__global__ __launch_bounds__(256)
void gemm1_mfma(const u16* __restrict__ Ah, const u16* __restrict__ Al,
                const u16* __restrict__ Bh, const u16* __restrict__ Bl,
                const float* __restrict__ bias, float* __restrict__ C) {
  __shared__ u16 Ash[128][PAD32];
  __shared__ u16 Asl[128][PAD32];
  __shared__ u16 Bsh[128][PAD32];
  __shared__ u16 Bsl[128][PAD32];
  const int tid  = threadIdx.x;
  const int lane = tid & 63, wave = tid >> 6;
  const int wm = wave >> 1, wn = wave & 1;
  const int l15 = lane & 15, k8 = (lane >> 4) * 8, r4 = (lane >> 4) * 4;
  const int row0 = blockIdx.y * 128, col0 = blockIdx.x * 128;
  const int srow = tid >> 1, sk = (tid & 1) * 16;

  const u16* pAh = Ah + (size_t)(row0 + srow) * Dd + sk;
  const u16* pAl = Al + (size_t)(row0 + srow) * Dd + sk;
  const u16* pBh = Bh + (size_t)(col0 + srow) * Dd + sk;
  const u16* pBl = Bl + (size_t)(col0 + srow) * Dd + sk;

  f32x4 acc[4][4];
#pragma unroll
  for (int i = 0; i < 4; ++i)
#pragma unroll
    for (int j = 0; j < 4; ++j) acc[i][j] = (f32x4){0.f, 0.f, 0.f, 0.f};

  for (int k0 = 0; k0 < Dd; k0 += 32) {
    *(bf16x8*)(&Ash[srow][sk])     = *(const bf16x8*)(pAh + k0);
    *(bf16x8*)(&Ash[srow][sk + 8]) = *(const bf16x8*)(pAh + k0 + 8);
    *(bf16x8*)(&Asl[srow][sk])     = *(const bf16x8*)(pAl + k0);
    *(bf16x8*)(&Asl[srow][sk + 8]) = *(const bf16x8*)(pAl + k0 + 8);
    *(bf16x8*)(&Bsh[srow][sk])     = *(const bf16x8*)(pBh + k0);
    *(bf16x8*)(&Bsh[srow][sk + 8]) = *(const bf16x8*)(pBh + k0 + 8);
    *(bf16x8*)(&Bsl[srow][sk])     = *(const bf16x8*)(pBl + k0);
    *(bf16x8*)(&Bsl[srow][sk + 8]) = *(const bf16x8*)(pBl + k0 + 8);
    __syncthreads();

    bf16x8 afh[4], afl[4], bfh[4], bfl[4];
#pragma unroll
    for (int mt = 0; mt < 4; ++mt) {
      afh[mt] = *(const bf16x8*)(&Ash[wm * 64 + mt * 16 + l15][k8]);
      afl[mt] = *(const bf16x8*)(&Asl[wm * 64 + mt * 16 + l15][k8]);
    }
#pragma unroll
    for (int nt = 0; nt < 4; ++nt) {
      bfh[nt] = *(const bf16x8*)(&Bsh[wn * 64 + nt * 16 + l15][k8]);
      bfl[nt] = *(const bf16x8*)(&Bsl[wn * 64 + nt * 16 + l15][k8]);
    }
#pragma unroll
    for (int mt = 0; mt < 4; ++mt)
#pragma unroll
      for (int nt = 0; nt < 4; ++nt) {
        acc[mt][nt] = __builtin_amdgcn_mfma_f32_16x16x32_bf16(
            afh[mt], bfh[nt], acc[mt][nt], 0, 0, 0);
        acc[mt][nt] = __builtin_amdgcn_mfma_f32_16x16x32_bf16(
            afh[mt], bfl[nt], acc[mt][nt], 0, 0, 0);
        acc[mt][nt] = __builtin_amdgcn_mfma_f32_16x16x32_bf16(
            afl[mt], bfh[nt], acc[mt][nt], 0, 0, 0);
      }
    __syncthreads();
  }

#pragma unroll
  for (int nt = 0; nt < 4; ++nt) {
    const int col = col0 + wn * 64 + nt * 16 + l15;
    const float bj = bias[col];
#pragma unroll
    for (int mt = 0; mt < 4; ++mt) {
      float* Cp = C + (size_t)(row0 + wm * 64 + mt * 16 + r4) * Gg + col;
#pragma unroll
      for (int r = 0; r < 4; ++r)
        Cp[(size_t)r * Gg] = acc[mt][nt][r] + bj;
    }
  }
}

// ---------------- MFMA bf16x3 GEMM: logits = h2 @ WoutT^T + bout --------
__global__ __launch_bounds__(256)
void gemm_proj(const u16* __restrict__ Ah, const u16* __restrict__ Al,
               const u16* __restrict__ Bh, const u16* __restrict__ Bl,
               const float* __restrict__ bout, float* __restrict__ logits) {
  __shared__ u16 Ash[128][PAD32];
  __shared__ u16 Asl[128][PAD32];
  __shared__ u16 Bsh[PC][PAD32];
  __shared__ u16 Bsl[PC][PAD32];
  const int tid  = threadIdx.x;
  const int lane = tid & 63, wave = tid >> 6;
  const int l15 = lane & 15, k8 = (lane >> 4) * 8, r4 = (lane >> 4) * 4;
  const int row0 = blockIdx.x * 128;
  const int srow = tid >> 1, sk = (tid & 1) * 16;

  const u16* pAh = Ah + (size_t)(row0 + srow) * Hh + sk;
  const u16* pAl = Al + (size_t)(row0 + srow) * Hh + sk;
  const u16* pBh = Bh + (size_t)srow * Hh + sk;
  const u16* pBl = Bl + (size_t)srow * Hh + sk;

  f32x4 acc[2][7];
#pragma unroll
  for (int i = 0; i < 2; ++i)
#pragma unroll
    for (int j = 0; j < 7; ++j) acc[i][j] = (f32x4){0.f, 0.f, 0.f, 0.f};

  for (int k0 = 0; k0 < Hh; k0 += 32) {
    *(bf16x8*)(&Ash[srow][sk])     = *(const bf16x8*)(pAh + k0);
    *(bf16x8*)(&Ash[srow][sk + 8]) = *(const bf16x8*)(pAh + k0 + 8);
    *(bf16x8*)(&Asl[srow][sk])     = *(const bf16x8*)(pAl + k0);
    *(bf16x8*)(&Asl[srow][sk + 8]) = *(const bf16x8*)(pAl + k0 + 8);
    if (srow < PC) {
      *(bf16x8*)(&Bsh[srow][sk])     = *(const bf16x8*)(pBh + k0);
      *(bf16x8*)(&Bsh[srow][sk + 8]) = *(const bf16x8*)(pBh + k0 + 8);
      *(bf16x8*)(&Bsl[srow][sk])     = *(const bf16x8*)(pBl + k0);
      *(bf16x8*)(&Bsl[srow][sk + 8]) = *(const bf16x8*)(pBl + k0 + 8);
    }
    __syncthreads();

    bf16x8 afh[2], afl[2], bfh[7], bfl[7];
#pragma unroll
    for (int mt = 0; mt < 2; ++mt) {
      afh[mt] = *(const bf16x8*)(&Ash[wave * 32 + mt * 16 + l15][k8]);
      afl[mt] = *(const bf16x8*)(&Asl[wave * 32 + mt * 16 + l15][k8]);
    }
#pragma unroll
    for (int nt = 0; nt < 7; ++nt) {
      bfh[nt] = *(const bf16x8*)(&Bsh[nt * 16 + l15][k8]);
      bfl[nt] = *(const bf16x8*)(&Bsl[nt * 16 + l15][k8]);
    }
#pragma unroll
    for (int mt = 0; mt < 2; ++mt)
#pragma unroll
      for (int nt = 0; nt < 7; ++nt) {
        acc[mt][nt] = __builtin_amdgcn_mfma_f32_16x16x32_bf16(
            afh[mt], bfh[nt], acc[mt][nt], 0, 0, 0);
        acc[mt][nt] = __builtin_amdgcn_mfma_f32_16x16x32_bf16(
            afh[mt], bfl[nt], acc[mt][nt], 0, 0, 0);
        acc[mt][nt] = __builtin_amdgcn_mfma_f32_16x16x32_bf16(
            afl[mt], bfh[nt], acc[mt][nt], 0, 0, 0);
      }
    __syncthreads();
  }

#pragma unroll
  for (int nt = 0; nt < 7; ++nt) {
    const int col = nt * 16 + l15;
    const float bj = (col < Cc) ? bout[col] : 0.f;
#pragma unroll
    for (int mt = 0; mt < 2; ++mt) {
      float* Lp = logits + (size_t)(row0 + wave * 32 + mt * 16 + r4) * PC + col;
#pragma unroll
      for (int r = 0; r < 4; ++r)
        Lp[(size_t)r * PC] = acc[mt][nt][r] + bj;
    }
  }
}

// ---------------- softmax + CE over logits rows ----------------
__global__ __launch_bounds__(256)
void softmax_ce(const float* __restrict__ logits, const int* __restrict__ labels,
                float* __restrict__ preds, float* __restrict__ ce) {
  const int lane = threadIdx.x & 63, wv = threadIdx.x >> 6;
  const int row = blockIdx.x * 4 + wv;
  const float* lg = logits + (size_t)row * PC;
  const bool a0 = (lane < Cc), a1 = (lane + 64 < Cc);
  const float v0 = a0 ? lg[lane] : -INFINITY;
  const float v1 = a1 ? lg[lane + 64] : -INFINITY;
  float m = fmaxf(v0, v1);
#pragma unroll
  for (int off = 32; off > 0; off >>= 1) m = fmaxf(m, __shfl_xor(m, off));
  const float e0 = a0 ? expf(v0 - m) : 0.f;
  const float e1 = a1 ? expf(v1 - m) : 0.f;
  float s = e0 + e1;
#pragma unroll
  for (int off = 32; off > 0; off >>= 1) s += __shfl_xor(s, off);
  if (a0) preds[(size_t)row * Cc + lane] = e0 / s;
  if (a1) preds[(size_t)row * Cc + lane + 64] = e1 / s;
  const int lab = labels[row];
  if (lab == lane)           ce[row] = logf(s) + m - v0;
  else if (lab == lane + 64) ce[row] = logf(s) + m - v1;
}

// ---------------- SGEMM (fp32 fallback if ws too small) ----------------
#define BM 128
#define BN 128
#define BK 16

__global__ __launch_bounds__(256)
void sgemm_bias(const float* __restrict__ A, const float* __restrict__ B,
                const float* __restrict__ bias, float* __restrict__ C,
                int M, int N, int K) {
  __shared__ float As[BK][BM];
  __shared__ float Bs[BK][BN];
  const int tid  = threadIdx.x;
  const int row0 = blockIdx.y * BM, col0 = blockIdx.x * BN;
  const int tr = (tid >> 4) << 3;
  const int tc = (tid & 15) << 3;

  float acc[8][8];
#pragma unroll
  for (int i = 0; i < 8; ++i)
#pragma unroll
    for (int j = 0; j < 8; ++j) acc[i][j] = 0.f;

  const int arow = tid >> 1;
  const int acol = (tid & 1) << 3;
  const int brow = tid >> 4;
  const int bcol = (tid & 15) << 3;
  const float* Ap = A + (size_t)(row0 + arow) * K + acol;
  const float* Bp = B + (size_t)brow * N + (col0 + bcol);

  for (int k0 = 0; k0 < K; k0 += BK) {
    const float4 a0 = *(const float4*)(Ap + k0);
    const float4 a1 = *(const float4*)(Ap + k0 + 4);
    const float4 bv0 = *(const float4*)(Bp + (size_t)k0 * N);
    const float4 bv1 = *(const float4*)(Bp + (size_t)k0 * N + 4);
    As[acol + 0][arow] = a0.x;
    As[acol + 1][arow] = a0.y;
    As[acol + 2][arow] = a0.z;
    As[acol + 3][arow] = a0.w;
    As[acol + 4][arow] = a1.x;
    As[acol + 5][arow] = a1.y;
    As[acol + 6][arow] = a1.z;
    As[acol + 7][arow] = a1.w;
    *(float4*)(&Bs[brow][bcol])     = bv0;
    *(float4*)(&Bs[brow][bcol + 4]) = bv1;
    __syncthreads();
#pragma unroll
    for (int k = 0; k < BK; ++k) {
      float a[8], b[8];
      *(float4*)(a)     = *(const float4*)(&As[k][tr]);
      *(float4*)(a + 4) = *(const float4*)(&As[k][tr + 4]);
      *(float4*)(b)     = *(const float4*)(&Bs[k][tc]);
      *(float4*)(b + 4) = *(const float4*)(&Bs[k][tc + 4]);
#pragma unroll
      for (int i = 0; i < 8; ++i)
#pragma unroll
        for (int j = 0; j < 8; ++j)
          acc[i][j] = fmaf(a[i], b[j], acc[i][j]);
    }
    __syncthreads();
  }

  float bj[8];
#pragma unroll
  for (int j = 0; j < 8; ++j) bj[j] = bias[col0 + tc + j];
#pragma unroll
  for (int i = 0; i < 8; ++i) {
    float* Cp = C + (size_t)(row0 + tr + i) * N + (col0 + tc);
    float4 o0, o1;
    o0.x = acc[i][0] + bj[0]; o0.y = acc[i][1] + bj[1];
    o0.z = acc[i][2] + bj[2]; o0.w = acc[i][3] + bj[3];
    o1.x = acc[i][4] + bj[4]; o1.y = acc[i][5] + bj[5];
    o1.z = acc[i][6] + bj[6]; o1.w = acc[i][7] + bj[7];
    *(float4*)(Cp)     = o0;
    *(float4*)(Cp + 4) = o1;
  }
}

// ---------------- MFMA fused step v6: 4 blocks/CU, odd-stride LDS -------
// Grid 1024: blocks 0..511 = L1 step t, 512..1023 = L2 step t-1.
// Block (bg,cg): 16 batches (bg*16..) x 16 vc cols {g*512 + cg*4 + m}.
// 4 waves = K-quarters (kh); partials summed via ex[4][16][17].
__global__ __launch_bounds__(256, 4)
void fused_step4(const float* __restrict__ pre,
                 const u16* __restrict__ WP1h, const u16* __restrict__ WP1l,
                 const u16* __restrict__ WP2h, const u16* __restrict__ WP2l,
                 const float* __restrict__ b2,
                 u16* __restrict__ h1hi, u16* __restrict__ h1lo,
                 u16* __restrict__ h2hi, u16* __restrict__ h2lo,
                 u16* __restrict__ h2fh, u16* __restrict__ h2fl,
                 float* __restrict__ c1, float* __restrict__ c2, int t) {
  __shared__ u16 Ah[2][16][PAD128], Al[2][16][PAD128];
  __shared__ u16 Bh[2][16][PAD128], Bl[2][16][PAD128];
  __shared__ float ex[4][16][17];   // [kh][batch16][vc]
  const int tid = threadIdx.x;
  const int lane = tid & 63, kh = tid >> 6;   // wave = K-quarter
  const int fr = lane & 15, f8 = (lane >> 4) * 8, r4 = (lane >> 4) * 4;
  const bool isL2 = blockIdx.x >= 512;
  const int idx = blockIdx.x & 511;
  const int cg = idx & 127, bg = idx >> 7;    // 128 col-groups x 4 b-groups
  const int b0 = bg * 16;

  // staging: A/B 16 rows x 128 k-chunk; 16 thr/row, 8 u16/thread
  const int hr = tid >> 4, hk = (tid & 15) * 8;

  f32x4 acc = {0.f, 0.f, 0.f, 0.f};
  bool have = false;
  float p0 = 0.f, p1 = 0.f, p2 = 0.f, p3 = 0.f;

  // epilogue ownership (tid < 64): (batch-local eb, m)
  const int eb = tid >> 2, em = tid & 3;
  const int col = cg * 4 + em;
  const int ci = (b0 + eb) * Hh + col;

  if (!isL2) {
    if (t >= Tt) return;
    if (tid < 64) {  // prefetch pre-gate inputs (hidden under matmul)
      const float* pp = pre + ((size_t)(b0 + eb) * Tt + t) * Gg + col;
      p0 = pp[0]; p1 = pp[512]; p2 = pp[1024]; p3 = pp[1536];
    }
    if (t > 0) {
      const int sl = (t - 1) & 1;
      const u16* A_h = h1hi + (sl << 15) + (b0 + hr) * 512 + hk;
      const u16* A_l = h1lo + (sl << 15) + (b0 + hr) * 512 + hk;
      const u16* B_h = WP1h + (size_t)(cg * 16 + hr) * 512 + hk;
      const u16* B_l = WP1l + (size_t)(cg * 16 + hr) * 512 + hk;

      bf16x8 ra, rl_, rbh, rbl;
      ra = *(const bf16x8*)(A_h);   rl_ = *(const bf16x8*)(A_l);
      rbh = *(const bf16x8*)(B_h);  rbl = *(const bf16x8*)(B_l);
      *(bf16x8*)&Ah[0][hr][hk] = ra;   *(bf16x8*)&Al[0][hr][hk] = rl_;
      *(bf16x8*)&Bh[0][hr][hk] = rbh;  *(bf16x8*)&Bl[0][hr][hk] = rbl;
      __syncthreads();

      for (int kc = 0; kc < 4; ++kc) {
        const int cur = kc & 1;
        if (kc < 3) {
          const int ko = (kc + 1) * 128;
          ra = *(const bf16x8*)(A_h + ko);   rl_ = *(const bf16x8*)(A_l + ko);
          rbh = *(const bf16x8*)(B_h + ko);  rbl = *(const bf16x8*)(B_l + ko);
        }
        {
          const int c0 = kh * 32 + f8;
          const bf16x8 afh = *(const bf16x8*)&Ah[cur][fr][c0];
          const bf16x8 afl = *(const bf16x8*)&Al[cur][fr][c0];
          const bf16x8 bfh = *(const bf16x8*)&Bh[cur][fr][c0];
          const bf16x8 bfl = *(const bf16x8*)&Bl[cur][fr][c0];
          acc = __builtin_amdgcn_mfma_f32_16x16x32_bf16(afh, bfh, acc, 0, 0, 0);
          acc = __builtin_amdgcn_mfma_f32_16x16x32_bf16(afh, bfl, acc, 0, 0, 0);
          acc = __builtin_amdgcn_mfma_f32_16x16x32_bf16(afl, bfh, acc, 0, 0, 0);
        }
        if (kc < 3) {
          const int nb = cur ^ 1;
          *(bf16x8*)&Ah[nb][hr][hk] = ra;   *(bf16x8*)&Al[nb][hr][hk] = rl_;
          *(bf16x8*)&Bh[nb][hr][hk] = rbh;  *(bf16x8*)&Bl[nb][hr][hk] = rbl;
        }
        __syncthreads();
      }
      have = true;
    }
  } else {
    if (t < 1) return;
    // merged K=1024: chunks 0-3 A=h1[t-1], 4-7 A=h2[t-2] (MFMA skipped t<2)
    const u16* A1h = h1hi + (((t - 1) & 1) << 15) + (b0 + hr) * 512 + hk;
    const u16* A1l = h1lo + (((t - 1) & 1) << 15) + (b0 + hr) * 512 + hk;
    const u16* A2h = h2hi + (((t - 2) & 1) << 15) + (b0 + hr) * 512 + hk;
    const u16* A2l = h2lo + (((t - 2) & 1) << 15) + (b0 + hr) * 512 + hk;
    const u16* B_h = WP2h + (size_t)(cg * 16 + hr) * 1024 + hk;
    const u16* B_l = WP2l + (size_t)(cg * 16 + hr) * 1024 + hk;
    const bool h2ok = (t >= 2);

    bf16x8 ra, rl_, rbh, rbl;
    ra = *(const bf16x8*)(A1h);   rl_ = *(const bf16x8*)(A1l);
    rbh = *(const bf16x8*)(B_h);  rbl = *(const bf16x8*)(B_l);
    *(bf16x8*)&Ah[0][hr][hk] = ra;   *(bf16x8*)&Al[0][hr][hk] = rl_;
    *(bf16x8*)&Bh[0][hr][hk] = rbh;  *(bf16x8*)&Bl[0][hr][hk] = rbl;
    __syncthreads();

    for (int kc = 0; kc < 8; ++kc) {
      const int cur = kc & 1;
      if (kc < 7) {
        const int nk = kc + 1;
        const u16* sh  = (nk < 4) ? A1h : A2h;
        const u16* sl2 = (nk < 4) ? A1l : A2l;
        const int ko = (nk & 3) * 128;
        ra = *(const bf16x8*)(sh + ko);    rl_ = *(const bf16x8*)(sl2 + ko);
        rbh = *(const bf16x8*)(B_h + nk * 128);
        rbl = *(const bf16x8*)(B_l + nk * 128);
      }
      if (kc < 4 || h2ok) {
        const int c0 = kh * 32 + f8;
        const bf16x8 afh = *(const bf16x8*)&Ah[cur][fr][c0];
        const bf16x8 afl = *(const bf16x8*)&Al[cur][fr][c0];
        const bf16x8 bfh = *(const bf16x8*)&Bh[cur][fr][c0];
        const bf16x8 bfl = *(const bf16x8*)&Bl[cur][fr][c0];
        acc = __builtin_amdgcn_mfma_f32_16x16x32_bf16(afh, bfh, acc, 0, 0, 0);
        acc = __builtin_amdgcn_mfma_f32_16x16x32_bf16(afh, bfl, acc, 0, 0, 0);
        acc = __builtin_amdgcn_mfma_f32_16x16x32_bf16(afl, bfh, acc, 0, 0, 0);
      }
      if (kc < 7) {
        const int nb = cur ^ 1;
        *(bf16x8*)&Ah[nb][hr][hk] = ra;   *(bf16x8*)&Al[nb][hr][hk] = rl_;
        *(bf16x8*)&Bh[nb][hr][hk] = rbh;  *(bf16x8*)&Bl[nb][hr][hk] = rbl;
      }
      __syncthreads();
    }
    have = true;
  }

  if (have) {
#pragma unroll
    for (int r = 0; r < 4; ++r)
      ex[kh][r4 + r][fr] = acc[r];
  }
  __syncthreads();

  if (tid < 64) {
    float s0 = 0.f, s1 = 0.f, s2 = 0.f, s3 = 0.f;
    if (have) {
#pragma unroll
      for (int q = 0; q < 4; ++q) {
        s0 += ex[q][eb][0 + em];
        s1 += ex[q][eb][4 + em];
        s2 += ex[q][eb][8 + em];
        s3 += ex[q][eb][12 + em];
      }
    }
    if (!isL2) {
      const float gi = p0 + s0, gj = p1 + s1, gf = p2 + s2, go = p3 + s3;
      const float cp = (t > 0) ? c1[ci] : 0.f;
      const float nc = fmaf(cp, sigm(gf + 1.f), sigm(gi) * tanhf(gj));
      c1[ci] = nc;
      const float nh = tanhf(nc) * sigm(go);
      u16 hh, hl;
      split_bf16(nh, hh, hl);
      const int hidx = ((t & 1) << 15) + ci;
      h1hi[hidx] = hh;
      h1lo[hidx] = hl;
    } else {
      const float gi = b2[col] + s0, gj = b2[512 + col] + s1;
      const float gf = b2[1024 + col] + s2, go = b2[1536 + col] + s3;
      const float cp = (t >= 2) ? c2[ci] : 0.f;
      const float nc = fmaf(cp, sigm(gf + 1.f), sigm(gi) * tanhf(gj));
      c2[ci] = nc;
      const float nh = tanhf(nc) * sigm(go);
      u16 hh, hl;
      split_bf16(nh, hh, hl);
      const int hidx = (((t - 1) & 1) << 15) + ci;
      h2hi[hidx] = hh;
      h2lo[hidx] = hl;
      const size_t fo = ((size_t)(b0 + eb) * Tt + (t - 1)) * Hh + col;
      h2fh[fo] = hh;
      h2fl[fo] = hl;
    }
  }
}

__global__ __launch_bounds__(256)
void reduce_cost(const float* __restrict__ ce, float* __restrict__ out) {
  __shared__ float red[256];
  const int tid = threadIdx.x;
  float s = 0.f;
  for (int i = tid; i < ROWS; i += 256) s += ce[i];
  red[tid] = s;
  __syncthreads();
  for (int st = 128; st > 0; st >>= 1) {
    if (tid < st) red[tid] += red[tid + st];
    __syncthreads();
  }
  if (tid == 0) out[0] = red[0] / (float)Bb;
}

// ---------------- launch ----------------
extern "C" void kernel_launch(void* const* d_in, const int* in_sizes, int n_in,
                              void* d_out, int out_size, void* d_ws, size_t ws_size,
                              hipStream_t stream) {
  const float* inputs = (const float*)d_in[0];
  const int*   labels = (const int*)d_in[1];
  const float* W1     = (const float*)d_in[2];
  const float* b1     = (const float*)d_in[3];
  const float* W2     = (const float*)d_in[4];
  const float* b2     = (const float*)d_in[5];
  const float* Wout   = (const float*)d_in[6];
  const float* bout   = (const float*)d_in[7];
  float* out = (float*)d_out;

  float* ws     = (float*)d_ws;
  float* pre    = ws;                              // ROWS*Gg   (16M f32)
  float* c1     = pre    + (size_t)ROWS * Gg;      // 64*512
  float* c2     = c1     + (size_t)Bb * Hh;
  float* ceb    = c2     + (size_t)Bb * Hh;        // ROWS
  float* logits = ceb    + ROWS;                   // ROWS*PC
  u16* h1hi = (u16*)(logits + (size_t)ROWS * PC);  // [2][64][512]
  u16* h1lo = h1hi + 2 * 64 * 512;
  u16* h2hi = h1lo + 2 * 64 * 512;
  u16* h2lo = h2hi + 2 * 64 * 512;
  u16* h2fh = h2lo + 2 * 64 * 512;                 // ROWS*Hh
  u16* h2fl = h2fh + (size_t)ROWS * Hh;
  u16* WP1h = h2fl + (size_t)ROWS * Hh;            // 128*16*512
  u16* WP1l = WP1h + 128 * 16 * 512;
  u16* WP2h = WP1l + 128 * 16 * 512;               // 128*16*1024
  u16* WP2l = WP2h + 128 * 16 * 1024;
  u16* WoTh = WP2l + 128 * 16 * 1024;              // PC*Hh
  u16* WoTl = WoTh + PC * Hh;
  u16* Xhi  = WoTl + PC * Hh;                      // ROWS*Dd
  u16* Xlo  = Xhi  + (size_t)ROWS * Dd;
  u16* W1Th = Xlo  + (size_t)ROWS * Dd;            // Gg*Dd
  u16* W1Tl = W1Th + (size_t)Gg * Dd;
  const size_t need = (size_t)((char*)(W1Tl + (size_t)Gg * Dd) - (char*)d_ws);
  const bool use_mfma = ws_size >= need;

  // weights: permute+split once
  permuteW<<<dim3(16, 64), dim3(32, 8), 0, stream>>>(
      W1 + (size_t)Dd * Gg, WP1h, WP1l, 512);
  permuteW<<<dim3(32, 64), dim3(32, 8), 0, stream>>>(W2, WP2h, WP2l, 1024);
  convert_woutT<<<PC, 256, 0, stream>>>(Wout, WoTh, WoTl);

  // Layer 1 input projection: pre = X @ W1[0:D,:] + b1
  if (use_mfma) {
    convert_hilo<<<2048, 256, 0, stream>>>(inputs, Xhi, Xlo, ROWS * Dd / 4);
    convertT_w1<<<dim3(64, 64), dim3(32, 8), 0, stream>>>(W1, W1Th, W1Tl);
    gemm1_mfma<<<dim3(Gg / 128, ROWS / 128), 256, 0, stream>>>(
        Xhi, Xlo, W1Th, W1Tl, b1, pre);
  } else {
    sgemm_bias<<<dim3(Gg / BN, ROWS / BM), dim3(256), 0, stream>>>(
        inputs, W1, b1, pre, ROWS, Gg, Dd);
  }

  // Recurrence: phase t = L1 step t (blocks 0..511) + L2 step t-1 (512..1023)
  for (int t = 0; t <= Tt; ++t)
    fused_step4<<<1024, 256, 0, stream>>>(pre, WP1h, WP1l, WP2h, WP2l, b2,
                                          h1hi, h1lo, h2hi, h2lo,
                                          h2fh, h2fl, c1, c2, t);

  // Output projection (MFMA) + softmax/CE + cost
  gemm_proj<<<ROWS / 128, 256, 0, stream>>>(h2fh, h2fl, WoTh, WoTl, bout, logits);
  softmax_ce<<<ROWS / 4, 256, 0, stream>>>(logits, labels, out, ceb);
  reduce_cost<<<1, 256, 0, stream>>>(ceb, out + (size_t)ROWS * Cc);
}

// Round 18
// 1504.659 us; speedup vs baseline: 1.1697x; 1.1697x over previous
//
#include <hip/hip_runtime.h>
#include <cmath>

// Problem constants
#define Bb   64
#define Tt   128
#define Dd   2048
#define Hh   512
#define Gg   2048      // 4*H
#define Cc   101
#define PC   112       // classes padded to 7*16 for MFMA
#define ROWS 8192      // B*T

typedef unsigned short u16;
typedef __attribute__((ext_vector_type(8))) short bf16x8;
typedef __attribute__((ext_vector_type(4))) float f32x4;

// LDS layout notes (R17 lesson): ds_read_b128 needs 16B-aligned rows, so
// row stride is always a multiple of 4 dwords -> odd-dword padding is
// IMPOSSIBLE for b128 tiles (R17's 42-u16 try split every access: conflicts
// 3.35e7 -> 5.03e7, gemm1 +50us). Correct tool: XOR-swizzle 16B slots
// within the row (T2/G4) - alignment kept, banks spread.
#define PAD32 40      // fused_step4 / gemm_proj: R16-proven padding
#define PAD128 136

// ---------------- bf16 hi/lo split helpers ----------------
__device__ __forceinline__ u16 bf16rne(float x) {
  unsigned u = __float_as_uint(x);
  unsigned r = (u + 0x7fffu + ((u >> 16) & 1u)) >> 16;
  return (u16)r;
}
__device__ __forceinline__ void split_bf16(float x, u16& h, u16& l) {
  h = bf16rne(x);
  l = bf16rne(x - __uint_as_float(((unsigned)h) << 16));
}
__device__ __forceinline__ float sigm(float x) { return 1.f / (1.f + expf(-x)); }

// X [ROWS x Dd] fp32 -> Xhi, Xlo bf16 (same layout)
__global__ __launch_bounds__(256)
void convert_hilo(const float* __restrict__ src, u16* __restrict__ hi,
                  u16* __restrict__ lo, int n4) {
  for (int i = blockIdx.x * 256 + threadIdx.x; i < n4; i += gridDim.x * 256) {
    const float4 v = ((const float4*)src)[i];
    ushort4 h, l;
    split_bf16(v.x, h.x, l.x);
    split_bf16(v.y, h.y, l.y);
    split_bf16(v.z, h.z, l.z);
    split_bf16(v.w, h.w, l.w);
    ((ushort4*)hi)[i] = h;
    ((ushort4*)lo)[i] = l;
  }
}

// W1 top [Dd x Gg] -> W1T hi/lo [Gg x Dd] bf16  (for gemm1 B operand)
__global__ __launch_bounds__(256)
void convertT_w1(const float* __restrict__ W1, u16* __restrict__ Th,
                 u16* __restrict__ Tl) {
  __shared__ float tl[32][33];
  const int tx = threadIdx.x, ty = threadIdx.y;   // 32, 8
  const int k0 = blockIdx.x * 32, c0 = blockIdx.y * 32;
#pragma unroll
  for (int j = 0; j < 4; ++j)
    tl[ty + j * 8][tx] = W1[(size_t)(k0 + ty + j * 8) * Gg + (c0 + tx)];
  __syncthreads();
#pragma unroll
  for (int j = 0; j < 4; ++j) {
    const float v = tl[tx][ty + j * 8];
    u16 h, l;
    split_bf16(v, h, l);
    const size_t o = (size_t)(c0 + ty + j * 8) * Dd + (k0 + tx);
    Th[o] = h;
    Tl[o] = l;
  }
}

// Wout [Hh x Cc] -> WoutT hi/lo [PC x Hh] (rows >= Cc zero)
__global__ __launch_bounds__(256)
void convert_woutT(const float* __restrict__ Wout, u16* __restrict__ Th,
                   u16* __restrict__ Tl) {
  const int c = blockIdx.x;
  for (int k = threadIdx.x; k < Hh; k += 256) {
    const float v = (c < Cc) ? Wout[k * Cc + c] : 0.f;
    u16 h, l;
    split_bf16(v, h, l);
    Th[c * Hh + k] = h;
    Tl[c * Hh + k] = l;
  }
}

// Recurrent weights, permuted + split:
// WP[cg 128][vc 16][K], vc = g*4 + m for col = g*512 + cg*4 + m.
__global__ __launch_bounds__(256)
void permuteW(const float* __restrict__ src, u16* __restrict__ dh,
              u16* __restrict__ dl, int K) {
  __shared__ float tl[32][33];
  const int tx = threadIdx.x, ty = threadIdx.y;   // 32, 8
  const int k0 = blockIdx.x * 32, c0 = blockIdx.y * 32;
#pragma unroll
  for (int j = 0; j < 4; ++j)
    tl[ty + j * 8][tx] = src[(size_t)(k0 + ty + j * 8) * Gg + (c0 + tx)];
  __syncthreads();
#pragma unroll
  for (int j = 0; j < 4; ++j) {
    const int col = c0 + ty + j * 8;
    const int g = col >> 9, mg = col & 511;
    const int cg = mg >> 2, m = mg & 3;
    const float v = tl[tx][ty + j * 8];
    u16 h, l;
    split_bf16(v, h, l);
    const size_t o = (size_t)(cg * 16 + g * 4 + m) * K + k0 + tx;
    dh[o] = h;
    dl[o] = l;
  }
}

// ---------------- MFMA bf16x3 GEMM: pre = X @ W1 + b1 ----------------
// LDS: [128][32] u16 unpadded; 16B slot s stored at s ^ (row & 3) (XOR
// swizzle) -> wave frag-read covers 16 full rows uniformly, aligned b128.
__global__ __launch_bounds__(256)
void gemm1_mfma(const u16* __restrict__ Ah, const u16* __restrict__ Al,
                const u16* __restrict__ Bh, const u16* __restrict__ Bl,
                const float* __restrict__ bias, float* __restrict__ C) {
  __shared__ u16 Ash[128][32];
  __shared__ u16 Asl[128][32];
  __shared__ u16 Bsh[128][32];
  __shared__ u16 Bsl[128][32];
  const int tid  = threadIdx.x;
  const int lane = tid & 63, wave = tid >> 6;
  const int wm = wave >> 1, wn = wave & 1;
  const int l15 = lane & 15, q = lane >> 4, r4 = (lane >> 4) * 4;
  const int row0 = blockIdx.y * 128, col0 = blockIdx.x * 128;
  const int srow = tid >> 1, sslot = (tid & 1) * 2;
  const int ws0 = ((sslot)     ^ (srow & 3)) * 8;   // swizzled write slots
  const int ws1 = ((sslot + 1) ^ (srow & 3)) * 8;

  const u16* pAh = Ah + (size_t)(row0 + srow) * Dd + sslot * 8;
  const u16* pAl = Al + (size_t)(row0 + srow) * Dd + sslot * 8;
  const u16* pBh = Bh + (size_t)(col0 + srow) * Dd + sslot * 8;
  const u16* pBl = Bl + (size_t)(col0 + srow) * Dd + sslot * 8;

  f32x4 acc[4][4];
#pragma unroll
  for (int i = 0; i < 4; ++i)
#pragma unroll
    for (int j = 0; j < 4; ++j) acc[i][j] = (f32x4){0.f, 0.f, 0.f, 0.f};

  for (int k0 = 0; k0 < Dd; k0 += 32) {
    *(bf16x8*)(&Ash[srow][ws0]) = *(const bf16x8*)(pAh + k0);
    *(bf16x8*)(&Ash[srow][ws1]) = *(const bf16x8*)(pAh + k0 + 8);
    *(bf16x8*)(&Asl[srow][ws0]) = *(const bf16x8*)(pAl + k0);
    *(bf16x8*)(&Asl[srow][ws1]) = *(const bf16x8*)(pAl + k0 + 8);
    *(bf16x8*)(&Bsh[srow][ws0]) = *(const bf16x8*)(pBh + k0);
    *(bf16x8*)(&Bsh[srow][ws1]) = *(const bf16x8*)(pBh + k0 + 8);
    *(bf16x8*)(&Bsl[srow][ws0]) = *(const bf16x8*)(pBl + k0);
    *(bf16x8*)(&Bsl[srow][ws1]) = *(const bf16x8*)(pBl + k0 + 8);
    __syncthreads();

    bf16x8 afh[4], afl[4], bfh[4], bfl[4];
#pragma unroll
    for (int mt = 0; mt < 4; ++mt) {
      const int row = wm * 64 + mt * 16 + l15;
      const int rs = (q ^ (row & 3)) * 8;
      afh[mt] = *(const bf16x8*)(&Ash[row][rs]);
      afl[mt] = *(const bf16x8*)(&Asl[row][rs]);
    }
#pragma unroll
    for (int nt = 0; nt < 4; ++nt) {
      const int row = wn * 64 + nt * 16 + l15;
      const int rs = (q ^ (row & 3)) * 8;
      bfh[nt] = *(const bf16x8*)(&Bsh[row][rs]);
      bfl[nt] = *(const bf16x8*)(&Bsl[row][rs]);
    }
#pragma unroll
    for (int mt = 0; mt < 4; ++mt)
#pragma unroll
      for (int nt = 0; nt < 4; ++nt) {
        acc[mt][nt] = __builtin_amdgcn_mfma_f32_16x16x32_bf16(
            afh[mt], bfh[nt], acc[mt][nt], 0, 0, 0);
        acc[mt][nt] = __builtin_amdgcn_mfma_f32_16x16x32_bf16(
            afh[mt], bfl[nt], acc[mt][nt], 0, 0, 0);
        acc[mt][nt] = __builtin_amdgcn_mfma_f32_16x16x32_bf16(
            afl[mt], bfh[nt], acc[mt][nt], 0, 0, 0);
      }
    __syncthreads();
  }

#pragma unroll
  for (int nt = 0; nt < 4; ++nt) {
    const int col = col0 + wn * 64 + nt * 16 + l15;
    const float bj = bias[col];
#pragma unroll
    for (int mt = 0; mt < 4; ++mt) {
      float* Cp = C + (size_t)(row0 + wm * 64 + mt * 16 + r4) * Gg + col;
#pragma unroll
      for (int r = 0; r < 4; ++r)
        Cp[(size_t)r * Gg] = acc[mt][nt][r] + bj;
    }
  }
}

// ---------------- MFMA bf16x3 GEMM: logits = h2 @ WoutT^T + bout --------
__global__ __launch_bounds__(256)
void gemm_proj(const u16* __restrict__ Ah, const u16* __restrict__ Al,
               const u16* __restrict__ Bh, const u16* __restrict__ Bl,
               const float* __restrict__ bout, float* __restrict__ logits) {
  __shared__ u16 Ash[128][PAD32];
  __shared__ u16 Asl[128][PAD32];
  __shared__ u16 Bsh[PC][PAD32];
  __shared__ u16 Bsl[PC][PAD32];
  const int tid  = threadIdx.x;
  const int lane = tid & 63, wave = tid >> 6;
  const int l15 = lane & 15, k8 = (lane >> 4) * 8, r4 = (lane >> 4) * 4;
  const int row0 = blockIdx.x * 128;
  const int srow = tid >> 1, sk = (tid & 1) * 16;

  const u16* pAh = Ah + (size_t)(row0 + srow) * Hh + sk;
  const u16* pAl = Al + (size_t)(row0 + srow) * Hh + sk;
  const u16* pBh = Bh + (size_t)srow * Hh + sk;
  const u16* pBl = Bl + (size_t)srow * Hh + sk;

  f32x4 acc[2][7];
#pragma unroll
  for (int i = 0; i < 2; ++i)
#pragma unroll
    for (int j = 0; j < 7; ++j) acc[i][j] = (f32x4){0.f, 0.f, 0.f, 0.f};

  for (int k0 = 0; k0 < Hh; k0 += 32) {
    *(bf16x8*)(&Ash[srow][sk])     = *(const bf16x8*)(pAh + k0);
    *(bf16x8*)(&Ash[srow][sk + 8]) = *(const bf16x8*)(pAh + k0 + 8);
    *(bf16x8*)(&Asl[srow][sk])     = *(const bf16x8*)(pAl + k0);
    *(bf16x8*)(&Asl[srow][sk + 8]) = *(const bf16x8*)(pAl + k0 + 8);
    if (srow < PC) {
      *(bf16x8*)(&Bsh[srow][sk])     = *(const bf16x8*)(pBh + k0);
      *(bf16x8*)(&Bsh[srow][sk + 8]) = *(const bf16x8*)(pBh + k0 + 8);
      *(bf16x8*)(&Bsl[srow][sk])     = *(const bf16x8*)(pBl + k0);
      *(bf16x8*)(&Bsl[srow][sk + 8]) = *(const bf16x8*)(pBl + k0 + 8);
    }
    __syncthreads();

    bf16x8 afh[2], afl[2], bfh[7], bfl[7];
#pragma unroll
    for (int mt = 0; mt < 2; ++mt) {
      afh[mt] = *(const bf16x8*)(&Ash[wave * 32 + mt * 16 + l15][k8]);
      afl[mt] = *(const bf16x8*)(&Asl[wave * 32 + mt * 16 + l15][k8]);
    }
#pragma unroll
    for (int nt = 0; nt < 7; ++nt) {
      bfh[nt] = *(const bf16x8*)(&Bsh[nt * 16 + l15][k8]);
      bfl[nt] = *(const bf16x8*)(&Bsl[nt * 16 + l15][k8]);
    }
#pragma unroll
    for (int mt = 0; mt < 2; ++mt)
#pragma unroll
      for (int nt = 0; nt < 7; ++nt) {
        acc[mt][nt] = __builtin_amdgcn_mfma_f32_16x16x32_bf16(
            afh[mt], bfh[nt], acc[mt][nt], 0, 0, 0);
        acc[mt][nt] = __builtin_amdgcn_mfma_f32_16x16x32_bf16(
            afh[mt], bfl[nt], acc[mt][nt], 0, 0, 0);
        acc[mt][nt] = __builtin_amdgcn_mfma_f32_16x16x32_bf16(
            afl[mt], bfh[nt], acc[mt][nt], 0, 0, 0);
      }
    __syncthreads();
  }

#pragma unroll
  for (int nt = 0; nt < 7; ++nt) {
    const int col = nt * 16 + l15;
    const float bj = (col < Cc) ? bout[col] : 0.f;
#pragma unroll
    for (int mt = 0; mt < 2; ++mt) {
      float* Lp = logits + (size_t)(row0 + wave * 32 + mt * 16 + r4) * PC + col;
#pragma unroll
      for (int r = 0; r < 4; ++r)
        Lp[(size_t)r * PC] = acc[mt][nt][r] + bj;
    }
  }
}

// ---------------- softmax + CE over logits rows ----------------
__global__ __launch_bounds__(256)
void softmax_ce(const float* __restrict__ logits, const int* __restrict__ labels,
                float* __restrict__ preds, float* __restrict__ ce) {
  const int lane = threadIdx.x & 63, wv = threadIdx.x >> 6;
  const int row = blockIdx.x * 4 + wv;
  const float* lg = logits + (size_t)row * PC;
  const bool a0 = (lane < Cc), a1 = (lane + 64 < Cc);
  const float v0 = a0 ? lg[lane] : -INFINITY;
  const float v1 = a1 ? lg[lane + 64] : -INFINITY;
  float m = fmaxf(v0, v1);
#pragma unroll
  for (int off = 32; off > 0; off >>= 1) m = fmaxf(m, __shfl_xor(m, off));
  const float e0 = a0 ? expf(v0 - m) : 0.f;
  const float e1 = a1 ? expf(v1 - m) : 0.f;
  float s = e0 + e1;
#pragma unroll
  for (int off = 32; off > 0; off >>= 1) s += __shfl_xor(s, off);
  if (a0) preds[(size_t)row * Cc + lane] = e0 / s;
  if (a1) preds[(size_t)row * Cc + lane + 64] = e1 / s;
  const int lab = labels[row];
  if (lab == lane)           ce[row] = logf(s) + m - v0;
  else if (lab == lane + 64) ce[row] = logf(s) + m - v1;
}

// ---------------- SGEMM (fp32 fallback if ws too small) ----------------
#define BM 128
#define BN 128
#define BK 16

__global__ __launch_bounds__(256)
void sgemm_bias(const float* __restrict__ A, const float* __restrict__ B,
                const float* __restrict__ bias, float* __restrict__ C,
                int M, int N, int K) {
  __shared__ float As[BK][BM];
  __shared__ float Bs[BK][BN];
  const int tid  = threadIdx.x;
  const int row0 = blockIdx.y * BM, col0 = blockIdx.x * BN;
  const int tr = (tid >> 4) << 3;
  const int tc = (tid & 15) << 3;

  float acc[8][8];
#pragma unroll
  for (int i = 0; i < 8; ++i)
#pragma unroll
    for (int j = 0; j < 8; ++j) acc[i][j] = 0.f;

  const int arow = tid >> 1;
  const int acol = (tid & 1) << 3;
  const int brow = tid >> 4;
  const int bcol = (tid & 15) << 3;
  const float* Ap = A + (size_t)(row0 + arow) * K + acol;
  const float* Bp = B + (size_t)brow * N + (col0 + bcol);

  for (int k0 = 0; k0 < K; k0 += BK) {
    const float4 a0 = *(const float4*)(Ap + k0);
    const float4 a1 = *(const float4*)(Ap + k0 + 4);
    const float4 bv0 = *(const float4*)(Bp + (size_t)k0 * N);
    const float4 bv1 = *(const float4*)(Bp + (size_t)k0 * N + 4);
    As[acol + 0][arow] = a0.x;
    As[acol + 1][arow] = a0.y;
    As[acol + 2][arow] = a0.z;
    As[acol + 3][arow] = a0.w;
    As[acol + 4][arow] = a1.x;
    As[acol + 5][arow] = a1.y;
    As[acol + 6][arow] = a1.z;
    As[acol + 7][arow] = a1.w;
    *(float4*)(&Bs[brow][bcol])     = bv0;
    *(float4*)(&Bs[brow][bcol + 4]) = bv1;
    __syncthreads();
#pragma unroll
    for (int k = 0; k < BK; ++k) {
      float a[8], b[8];
      *(float4*)(a)     = *(const float4*)(&As[k][tr]);
      *(float4*)(a + 4) = *(const float4*)(&As[k][tr + 4]);
      *(float4*)(b)     = *(const float4*)(&Bs[k][tc]);
      *(float4*)(b + 4) = *(const float4*)(&Bs[k][tc + 4]);
#pragma unroll
      for (int i = 0; i < 8; ++i)
#pragma unroll
        for (int j = 0; j < 8; ++j)
          acc[i][j] = fmaf(a[i], b[j], acc[i][j]);
    }
    __syncthreads();
  }

  float bj[8];
#pragma unroll
  for (int j = 0; j < 8; ++j) bj[j] = bias[col0 + tc + j];
#pragma unroll
  for (int i = 0; i < 8; ++i) {
    float* Cp = C + (size_t)(row0 + tr + i) * N + (col0 + tc);
    float4 o0, o1;
    o0.x = acc[i][0] + bj[0]; o0.y = acc[i][1] + bj[1];
    o0.z = acc[i][2] + bj[2]; o0.w = acc[i][3] + bj[3];
    o1.x = acc[i][4] + bj[4]; o1.y = acc[i][5] + bj[5];
    o1.z = acc[i][6] + bj[6]; o1.w = acc[i][7] + bj[7];
    *(float4*)(Cp)     = o0;
    *(float4*)(Cp + 4) = o1;
  }
}

// ---------------- MFMA fused step v6: 4 blocks/CU (R16-proven layout) ---
// Grid 1024: blocks 0..511 = L1 step t, 512..1023 = L2 step t-1.
// Block (bg,cg): 16 batches (bg*16..) x 16 vc cols {g*512 + cg*4 + m}.
// 4 waves = K-quarters (kh); partials summed via ex[4][16][17].
__global__ __launch_bounds__(256, 4)
void fused_step4(const float* __restrict__ pre,
                 const u16* __restrict__ WP1h, const u16* __restrict__ WP1l,
                 const u16* __restrict__ WP2h, const u16* __restrict__ WP2l,
                 const float* __restrict__ b2,
                 u16* __restrict__ h1hi, u16* __restrict__ h1lo,
                 u16* __restrict__ h2hi, u16* __restrict__ h2lo,
                 u16* __restrict__ h2fh, u16* __restrict__ h2fl,
                 float* __restrict__ c1, float* __restrict__ c2, int t) {
  __shared__ u16 Ah[2][16][PAD128], Al[2][16][PAD128];
  __shared__ u16 Bh[2][16][PAD128], Bl[2][16][PAD128];
  __shared__ float ex[4][16][17];   // [kh][batch16][vc]
  const int tid = threadIdx.x;
  const int lane = tid & 63, kh = tid >> 6;   // wave = K-quarter
  const int fr = lane & 15, f8 = (lane >> 4) * 8, r4 = (lane >> 4) * 4;
  const bool isL2 = blockIdx.x >= 512;
  const int idx = blockIdx.x & 511;
  const int cg = idx & 127, bg = idx >> 7;    // 128 col-groups x 4 b-groups
  const int b0 = bg * 16;

  // staging: A/B 16 rows x 128 k-chunk; 16 thr/row, 8 u16/thread
  const int hr = tid >> 4, hk = (tid & 15) * 8;

  f32x4 acc = {0.f, 0.f, 0.f, 0.f};
  bool have = false;
  float p0 = 0.f, p1 = 0.f, p2 = 0.f, p3 = 0.f;

  // epilogue ownership (tid < 64): (batch-local eb, m)
  const int eb = tid >> 2, em = tid & 3;
  const int col = cg * 4 + em;
  const int ci = (b0 + eb) * Hh + col;

  if (!isL2) {
    if (t >= Tt) return;
    if (tid < 64) {  // prefetch pre-gate inputs (hidden under matmul)
      const float* pp = pre + ((size_t)(b0 + eb) * Tt + t) * Gg + col;
      p0 = pp[0]; p1 = pp[512]; p2 = pp[1024]; p3 = pp[1536];
    }
    if (t > 0) {
      const int sl = (t - 1) & 1;
      const u16* A_h = h1hi + (sl << 15) + (b0 + hr) * 512 + hk;
      const u16* A_l = h1lo + (sl << 15) + (b0 + hr) * 512 + hk;
      const u16* B_h = WP1h + (size_t)(cg * 16 + hr) * 512 + hk;
      const u16* B_l = WP1l + (size_t)(cg * 16 + hr) * 512 + hk;

      bf16x8 ra, rl_, rbh, rbl;
      ra = *(const bf16x8*)(A_h);   rl_ = *(const bf16x8*)(A_l);
      rbh = *(const bf16x8*)(B_h);  rbl = *(const bf16x8*)(B_l);
      *(bf16x8*)&Ah[0][hr][hk] = ra;   *(bf16x8*)&Al[0][hr][hk] = rl_;
      *(bf16x8*)&Bh[0][hr][hk] = rbh;  *(bf16x8*)&Bl[0][hr][hk] = rbl;
      __syncthreads();

      for (int kc = 0; kc < 4; ++kc) {
        const int cur = kc & 1;
        if (kc < 3) {
          const int ko = (kc + 1) * 128;
          ra = *(const bf16x8*)(A_h + ko);   rl_ = *(const bf16x8*)(A_l + ko);
          rbh = *(const bf16x8*)(B_h + ko);  rbl = *(const bf16x8*)(B_l + ko);
        }
        {
          const int c0 = kh * 32 + f8;
          const bf16x8 afh = *(const bf16x8*)&Ah[cur][fr][c0];
          const bf16x8 afl = *(const bf16x8*)&Al[cur][fr][c0];
          const bf16x8 bfh = *(const bf16x8*)&Bh[cur][fr][c0];
          const bf16x8 bfl = *(const bf16x8*)&Bl[cur][fr][c0];
          acc = __builtin_amdgcn_mfma_f32_16x16x32_bf16(afh, bfh, acc, 0, 0, 0);
          acc = __builtin_amdgcn_mfma_f32_16x16x32_bf16(afh, bfl, acc, 0, 0, 0);
          acc = __builtin_amdgcn_mfma_f32_16x16x32_bf16(afl, bfh, acc, 0, 0, 0);
        }
        if (kc < 3) {
          const int nb = cur ^ 1;
          *(bf16x8*)&Ah[nb][hr][hk] = ra;   *(bf16x8*)&Al[nb][hr][hk] = rl_;
          *(bf16x8*)&Bh[nb][hr][hk] = rbh;  *(bf16x8*)&Bl[nb][hr][hk] = rbl;
        }
        __syncthreads();
      }
      have = true;
    }
  } else {
    if (t < 1) return;
    // merged K=1024: chunks 0-3 A=h1[t-1], 4-7 A=h2[t-2] (MFMA skipped t<2)
    const u16* A1h = h1hi + (((t - 1) & 1) << 15) + (b0 + hr) * 512 + hk;
    const u16* A1l = h1lo + (((t - 1) & 1) << 15) + (b0 + hr) * 512 + hk;
    const u16* A2h = h2hi + (((t - 2) & 1) << 15) + (b0 + hr) * 512 + hk;
    const u16* A2l = h2lo + (((t - 2) & 1) << 15) + (b0 + hr) * 512 + hk;
    const u16* B_h = WP2h + (size_t)(cg * 16 + hr) * 1024 + hk;
    const u16* B_l = WP2l + (size_t)(cg * 16 + hr) * 1024 + hk;
    const bool h2ok = (t >= 2);

    bf16x8 ra, rl_, rbh, rbl;
    ra = *(const bf16x8*)(A1h);   rl_ = *(const bf16x8*)(A1l);
    rbh = *(const bf16x8*)(B_h);  rbl = *(const bf16x8*)(B_l);
    *(bf16x8*)&Ah[0][hr][hk] = ra;   *(bf16x8*)&Al[0][hr][hk] = rl_;
    *(bf16x8*)&Bh[0][hr][hk] = rbh;  *(bf16x8*)&Bl[0][hr][hk] = rbl;
    __syncthreads();

    for (int kc = 0; kc < 8; ++kc) {
      const int cur = kc & 1;
      if (kc < 7) {
        const int nk = kc + 1;
        const u16* sh  = (nk < 4) ? A1h : A2h;
        const u16* sl2 = (nk < 4) ? A1l : A2l;
        const int ko = (nk & 3) * 128;
        ra = *(const bf16x8*)(sh + ko);    rl_ = *(const bf16x8*)(sl2 + ko);
        rbh = *(const bf16x8*)(B_h + nk * 128);
        rbl = *(const bf16x8*)(B_l + nk * 128);
      }
      if (kc < 4 || h2ok) {
        const int c0 = kh * 32 + f8;
        const bf16x8 afh = *(const bf16x8*)&Ah[cur][fr][c0];
        const bf16x8 afl = *(const bf16x8*)&Al[cur][fr][c0];
        const bf16x8 bfh = *(const bf16x8*)&Bh[cur][fr][c0];
        const bf16x8 bfl = *(const bf16x8*)&Bl[cur][fr][c0];
        acc = __builtin_amdgcn_mfma_f32_16x16x32_bf16(afh, bfh, acc, 0, 0, 0);
        acc = __builtin_amdgcn_mfma_f32_16x16x32_bf16(afh, bfl, acc, 0, 0, 0);
        acc = __builtin_amdgcn_mfma_f32_16x16x32_bf16(afl, bfh, acc, 0, 0, 0);
      }
      if (kc < 7) {
        const int nb = cur ^ 1;
        *(bf16x8*)&Ah[nb][hr][hk] = ra;   *(bf16x8*)&Al[nb][hr][hk] = rl_;
        *(bf16x8*)&Bh[nb][hr][hk] = rbh;  *(bf16x8*)&Bl[nb][hr][hk] = rbl;
      }
      __syncthreads();
    }
    have = true;
  }

  if (have) {
#pragma unroll
    for (int r = 0; r < 4; ++r)
      ex[kh][r4 + r][fr] = acc[r];
  }
  __syncthreads();

  if (tid < 64) {
    float s0 = 0.f, s1 = 0.f, s2 = 0.f, s3 = 0.f;
    if (have) {
#pragma unroll
      for (int q = 0; q < 4; ++q) {
        s0 += ex[q][eb][0 + em];
        s1 += ex[q][eb][4 + em];
        s2 += ex[q][eb][8 + em];
        s3 += ex[q][eb][12 + em];
      }
    }
    if (!isL2) {
      const float gi = p0 + s0, gj = p1 + s1, gf = p2 + s2, go = p3 + s3;
      const float cp = (t > 0) ? c1[ci] : 0.f;
      const float nc = fmaf(cp, sigm(gf + 1.f), sigm(gi) * tanhf(gj));
      c1[ci] = nc;
      const float nh = tanhf(nc) * sigm(go);
      u16 hh, hl;
      split_bf16(nh, hh, hl);
      const int hidx = ((t & 1) << 15) + ci;
      h1hi[hidx] = hh;
      h1lo[hidx] = hl;
    } else {
      const float gi = b2[col] + s0, gj = b2[512 + col] + s1;
      const float gf = b2[1024 + col] + s2, go = b2[1536 + col] + s3;
      const float cp = (t >= 2) ? c2[ci] : 0.f;
      const float nc = fmaf(cp, sigm(gf + 1.f), sigm(gi) * tanhf(gj));
      c2[ci] = nc;
      const float nh = tanhf(nc) * sigm(go);
      u16 hh, hl;
      split_bf16(nh, hh, hl);
      const int hidx = (((t - 1) & 1) << 15) + ci;
      h2hi[hidx] = hh;
      h2lo[hidx] = hl;
      const size_t fo = ((size_t)(b0 + eb) * Tt + (t - 1)) * Hh + col;
      h2fh[fo] = hh;
      h2fl[fo] = hl;
    }
  }
}

__global__ __launch_bounds__(256)
void reduce_cost(const float* __restrict__ ce, float* __restrict__ out) {
  __shared__ float red[256];
  const int tid = threadIdx.x;
  float s = 0.f;
  for (int i = tid; i < ROWS; i += 256) s += ce[i];
  red[tid] = s;
  __syncthreads();
  for (int st = 128; st > 0; st >>= 1) {
    if (tid < st) red[tid] += red[tid + st];
    __syncthreads();
  }
  if (tid == 0) out[0] = red[0] / (float)Bb;
}

// ---------------- launch ----------------
extern "C" void kernel_launch(void* const* d_in, const int* in_sizes, int n_in,
                              void* d_out, int out_size, void* d_ws, size_t ws_size,
                              hipStream_t stream) {
  const float* inputs = (const float*)d_in[0];
  const int*   labels = (const int*)d_in[1];
  const float* W1     = (const float*)d_in[2];
  const float* b1     = (const float*)d_in[3];
  const float* W2     = (const float*)d_in[4];
  const float* b2     = (const float*)d_in[5];
  const float* Wout   = (const float*)d_in[6];
  const float* bout   = (const float*)d_in[7];
  float* out = (float*)d_out;

  float* ws     = (float*)d_ws;
  float* pre    = ws;                              // ROWS*Gg   (16M f32)
  float* c1     = pre    + (size_t)ROWS * Gg;      // 64*512
  float* c2     = c1     + (size_t)Bb * Hh;
  float* ceb    = c2     + (size_t)Bb * Hh;        // ROWS
  float* logits = ceb    + ROWS;                   // ROWS*PC
  u16* h1hi = (u16*)(logits + (size_t)ROWS * PC);  // [2][64][512]
  u16* h1lo = h1hi + 2 * 64 * 512;
  u16* h2hi = h1lo + 2 * 64 * 512;
  u16* h2lo = h2hi + 2 * 64 * 512;
  u16* h2fh = h2lo + 2 * 64 * 512;                 // ROWS*Hh
  u16* h2fl = h2fh + (size_t)ROWS * Hh;
  u16* WP1h = h2fl + (size_t)ROWS * Hh;            // 128*16*512
  u16* WP1l = WP1h + 128 * 16 * 512;
  u16* WP2h = WP1l + 128 * 16 * 512;               // 128*16*1024
  u16* WP2l = WP2h + 128 * 16 * 1024;
  u16* WoTh = WP2l + 128 * 16 * 1024;              // PC*Hh
  u16* WoTl = WoTh + PC * Hh;
  u16* Xhi  = WoTl + PC * Hh;                      // ROWS*Dd
  u16* Xlo  = Xhi  + (size_t)ROWS * Dd;
  u16* W1Th = Xlo  + (size_t)ROWS * Dd;            // Gg*Dd
  u16* W1Tl = W1Th + (size_t)Gg * Dd;
  const size_t need = (size_t)((char*)(W1Tl + (size_t)Gg * Dd) - (char*)d_ws);
  const bool use_mfma = ws_size >= need;

  // weights: permute+split once
  permuteW<<<dim3(16, 64), dim3(32, 8), 0, stream>>>(
      W1 + (size_t)Dd * Gg, WP1h, WP1l, 512);
  permuteW<<<dim3(32, 64), dim3(32, 8), 0, stream>>>(W2, WP2h, WP2l, 1024);
  convert_woutT<<<PC, 256, 0, stream>>>(Wout, WoTh, WoTl);

  // Layer 1 input projection: pre = X @ W1[0:D,:] + b1
  if (use_mfma) {
    convert_hilo<<<2048, 256, 0, stream>>>(inputs, Xhi, Xlo, ROWS * Dd / 4);
    convertT_w1<<<dim3(64, 64), dim3(32, 8), 0, stream>>>(W1, W1Th, W1Tl);
    gemm1_mfma<<<dim3(Gg / 128, ROWS / 128), 256, 0, stream>>>(
        Xhi, Xlo, W1Th, W1Tl, b1, pre);
  } else {
    sgemm_bias<<<dim3(Gg / BN, ROWS / BM), dim3(256), 0, stream>>>(
        inputs, W1, b1, pre, ROWS, Gg, Dd);
  }

  // Recurrence: phase t = L1 step t (blocks 0..511) + L2 step t-1 (512..1023)
  for (int t = 0; t <= Tt; ++t)
    fused_step4<<<1024, 256, 0, stream>>>(pre, WP1h, WP1l, WP2h, WP2l, b2,
                                          h1hi, h1lo, h2hi, h2lo,
                                          h2fh, h2fl, c1, c2, t);

  // Output projection (MFMA) + softmax/CE + cost
  gemm_proj<<<ROWS / 128, 256, 0, stream>>>(h2fh, h2fl, WoTh, WoTl, bout, logits);
  softmax_ce<<<ROWS / 4, 256, 0, stream>>>(logits, labels, out, ceb);
  reduce_cost<<<1, 256, 0, stream>>>(ceb, out + (size_t)ROWS * Cc);
}

// Round 19
// 1497.046 us; speedup vs baseline: 1.1757x; 1.0051x over previous
//
#include <hip/hip_runtime.h>
#include <cmath>

// Problem constants
#define Bb   64
#define Tt   128
#define Dd   2048
#define Hh   512
#define Gg   2048      // 4*H
#define Cc   101
#define PC   112       // classes padded to 7*16 for MFMA
#define ROWS 8192      // B*T

typedef unsigned short u16;
typedef __attribute__((ext_vector_type(8))) short bf16x8;
typedef __attribute__((ext_vector_type(4))) float f32x4;

// LDS notes (R17 lesson): ds_read_b128 needs 16B-aligned rows -> odd-dword
// padding impossible; use XOR slot swizzle (gemm1) or even padding (others).
#define PAD32 40
#define PAD128 136

// ---------------- bf16 hi/lo split helpers ----------------
__device__ __forceinline__ u16 bf16rne(float x) {
  unsigned u = __float_as_uint(x);
  unsigned r = (u + 0x7fffu + ((u >> 16) & 1u)) >> 16;
  return (u16)r;
}
__device__ __forceinline__ void split_bf16(float x, u16& h, u16& l) {
  h = bf16rne(x);
  l = bf16rne(x - __uint_as_float(((unsigned)h) << 16));
}
__device__ __forceinline__ float sigm(float x) { return 1.f / (1.f + expf(-x)); }

// X [ROWS x Dd] fp32 -> Xhi, Xlo bf16 (same layout)
__global__ __launch_bounds__(256)
void convert_hilo(const float* __restrict__ src, u16* __restrict__ hi,
                  u16* __restrict__ lo, int n4) {
  for (int i = blockIdx.x * 256 + threadIdx.x; i < n4; i += gridDim.x * 256) {
    const float4 v = ((const float4*)src)[i];
    ushort4 h, l;
    split_bf16(v.x, h.x, l.x);
    split_bf16(v.y, h.y, l.y);
    split_bf16(v.z, h.z, l.z);
    split_bf16(v.w, h.w, l.w);
    ((ushort4*)hi)[i] = h;
    ((ushort4*)lo)[i] = l;
  }
}

// W1 top [Dd x Gg] -> W1T hi/lo [Gg x Dd] bf16  (for gemm1 B operand)
__global__ __launch_bounds__(256)
void convertT_w1(const float* __restrict__ W1, u16* __restrict__ Th,
                 u16* __restrict__ Tl) {
  __shared__ float tl[32][33];
  const int tx = threadIdx.x, ty = threadIdx.y;   // 32, 8
  const int k0 = blockIdx.x * 32, c0 = blockIdx.y * 32;
#pragma unroll
  for (int j = 0; j < 4; ++j)
    tl[ty + j * 8][tx] = W1[(size_t)(k0 + ty + j * 8) * Gg + (c0 + tx)];
  __syncthreads();
#pragma unroll
  for (int j = 0; j < 4; ++j) {
    const float v = tl[tx][ty + j * 8];
    u16 h, l;
    split_bf16(v, h, l);
    const size_t o = (size_t)(c0 + ty + j * 8) * Dd + (k0 + tx);
    Th[o] = h;
    Tl[o] = l;
  }
}

// Wout [Hh x Cc] -> WoutT hi/lo [PC x Hh] (rows >= Cc zero)
__global__ __launch_bounds__(256)
void convert_woutT(const float* __restrict__ Wout, u16* __restrict__ Th,
                   u16* __restrict__ Tl) {
  const int c = blockIdx.x;
  for (int k = threadIdx.x; k < Hh; k += 256) {
    const float v = (c < Cc) ? Wout[k * Cc + c] : 0.f;
    u16 h, l;
    split_bf16(v, h, l);
    Th[c * Hh + k] = h;
    Tl[c * Hh + k] = l;
  }
}

// Recurrent weights, permuted + split:
// WP[cg 128][vc 16][K], vc = g*4 + m for col = g*512 + cg*4 + m.
__global__ __launch_bounds__(256)
void permuteW(const float* __restrict__ src, u16* __restrict__ dh,
              u16* __restrict__ dl, int K) {
  __shared__ float tl[32][33];
  const int tx = threadIdx.x, ty = threadIdx.y;   // 32, 8
  const int k0 = blockIdx.x * 32, c0 = blockIdx.y * 32;
#pragma unroll
  for (int j = 0; j < 4; ++j)
    tl[ty + j * 8][tx] = src[(size_t)(k0 + ty + j * 8) * Gg + (c0 + tx)];
  __syncthreads();
#pragma unroll
  for (int j = 0; j < 4; ++j) {
    const int col = c0 + ty + j * 8;
    const int g = col >> 9, mg = col & 511;
    const int cg = mg >> 2, m = mg & 3;
    const float v = tl[tx][ty + j * 8];
    u16 h, l;
    split_bf16(v, h, l);
    const size_t o = (size_t)(cg * 16 + g * 4 + m) * K + k0 + tx;
    dh[o] = h;
    dl[o] = l;
  }
}

// ---------------- MFMA bf16x3 GEMM: pre = X @ W1 + b1 ----------------
// 1D grid 1024, XCD-aware swizzle (T1): xcd x = lin&7 owns B col-blocks
// {2x, 2x+1} (2MB B-slice fits per-XCD 4MB L2; measured 2.2x HBM over-fetch
// without it: 365MB/dispatch at 1.49TB/s). Consecutive slots share A tile.
__global__ __launch_bounds__(256)
void gemm1_mfma(const u16* __restrict__ Ah, const u16* __restrict__ Al,
                const u16* __restrict__ Bh, const u16* __restrict__ Bl,
                const float* __restrict__ bias, float* __restrict__ C) {
  __shared__ u16 Ash[128][32];
  __shared__ u16 Asl[128][32];
  __shared__ u16 Bsh[128][32];
  __shared__ u16 Bsl[128][32];
  const int tid  = threadIdx.x;
  const int lane = tid & 63, wave = tid >> 6;
  const int wm = wave >> 1, wn = wave & 1;
  const int l15 = lane & 15, q = lane >> 4, r4 = (lane >> 4) * 4;
  // XCD swizzle: lin -> (bx, by)
  const int lin = blockIdx.x;
  const int xcd = lin & 7, s = lin >> 3;
  const int bx = 2 * xcd + (s & 1);     // col-block 0..15
  const int by = s >> 1;                // row-block 0..63
  const int row0 = by * 128, col0 = bx * 128;
  const int srow = tid >> 1, sslot = (tid & 1) * 2;
  const int ws0 = ((sslot)     ^ (srow & 3)) * 8;
  const int ws1 = ((sslot + 1) ^ (srow & 3)) * 8;

  const u16* pAh = Ah + (size_t)(row0 + srow) * Dd + sslot * 8;
  const u16* pAl = Al + (size_t)(row0 + srow) * Dd + sslot * 8;
  const u16* pBh = Bh + (size_t)(col0 + srow) * Dd + sslot * 8;
  const u16* pBl = Bl + (size_t)(col0 + srow) * Dd + sslot * 8;

  f32x4 acc[4][4];
#pragma unroll
  for (int i = 0; i < 4; ++i)
#pragma unroll
    for (int j = 0; j < 4; ++j) acc[i][j] = (f32x4){0.f, 0.f, 0.f, 0.f};

  for (int k0 = 0; k0 < Dd; k0 += 32) {
    *(bf16x8*)(&Ash[srow][ws0]) = *(const bf16x8*)(pAh + k0);
    *(bf16x8*)(&Ash[srow][ws1]) = *(const bf16x8*)(pAh + k0 + 8);
    *(bf16x8*)(&Asl[srow][ws0]) = *(const bf16x8*)(pAl + k0);
    *(bf16x8*)(&Asl[srow][ws1]) = *(const bf16x8*)(pAl + k0 + 8);
    *(bf16x8*)(&Bsh[srow][ws0]) = *(const bf16x8*)(pBh + k0);
    *(bf16x8*)(&Bsh[srow][ws1]) = *(const bf16x8*)(pBh + k0 + 8);
    *(bf16x8*)(&Bsl[srow][ws0]) = *(const bf16x8*)(pBl + k0);
    *(bf16x8*)(&Bsl[srow][ws1]) = *(const bf16x8*)(pBl + k0 + 8);
    __syncthreads();

    bf16x8 afh[4], afl[4], bfh[4], bfl[4];
#pragma unroll
    for (int mt = 0; mt < 4; ++mt) {
      const int row = wm * 64 + mt * 16 + l15;
      const int rs = (q ^ (row & 3)) * 8;
      afh[mt] = *(const bf16x8*)(&Ash[row][rs]);
      afl[mt] = *(const bf16x8*)(&Asl[row][rs]);
    }
#pragma unroll
    for (int nt = 0; nt < 4; ++nt) {
      const int row = wn * 64 + nt * 16 + l15;
      const int rs = (q ^ (row & 3)) * 8;
      bfh[nt] = *(const bf16x8*)(&Bsh[row][rs]);
      bfl[nt] = *(const bf16x8*)(&Bsl[row][rs]);
    }
#pragma unroll
    for (int mt = 0; mt < 4; ++mt)
#pragma unroll
      for (int nt = 0; nt < 4; ++nt) {
        acc[mt][nt] = __builtin_amdgcn_mfma_f32_16x16x32_bf16(
            afh[mt], bfh[nt], acc[mt][nt], 0, 0, 0);
        acc[mt][nt] = __builtin_amdgcn_mfma_f32_16x16x32_bf16(
            afh[mt], bfl[nt], acc[mt][nt], 0, 0, 0);
        acc[mt][nt] = __builtin_amdgcn_mfma_f32_16x16x32_bf16(
            afl[mt], bfh[nt], acc[mt][nt], 0, 0, 0);
      }
    __syncthreads();
  }

#pragma unroll
  for (int nt = 0; nt < 4; ++nt) {
    const int col = col0 + wn * 64 + nt * 16 + l15;
    const float bj = bias[col];
#pragma unroll
    for (int mt = 0; mt < 4; ++mt) {
      float* Cp = C + (size_t)(row0 + wm * 64 + mt * 16 + r4) * Gg + col;
#pragma unroll
      for (int r = 0; r < 4; ++r)
        Cp[(size_t)r * Gg] = acc[mt][nt][r] + bj;
    }
  }
}

// ---------------- MFMA proj + fused softmax/CE ----------------
// logits = h2 @ WoutT^T + bout computed in-register; each 16-lane quad
// holds a full row (7 regs x 16 lanes) -> quad-local shfl softmax; writes
// preds and ce directly (no logits buffer, no separate softmax kernel).
__global__ __launch_bounds__(256)
void gemm_proj(const u16* __restrict__ Ah, const u16* __restrict__ Al,
               const u16* __restrict__ Bh, const u16* __restrict__ Bl,
               const float* __restrict__ bout, const int* __restrict__ labels,
               float* __restrict__ preds, float* __restrict__ ce) {
  __shared__ u16 Ash[128][PAD32];
  __shared__ u16 Asl[128][PAD32];
  __shared__ u16 Bsh[PC][PAD32];
  __shared__ u16 Bsl[PC][PAD32];
  const int tid  = threadIdx.x;
  const int lane = tid & 63, wave = tid >> 6;
  const int l15 = lane & 15, k8 = (lane >> 4) * 8, r4 = (lane >> 4) * 4;
  const int row0 = blockIdx.x * 128;
  const int srow = tid >> 1, sk = (tid & 1) * 16;

  const u16* pAh = Ah + (size_t)(row0 + srow) * Hh + sk;
  const u16* pAl = Al + (size_t)(row0 + srow) * Hh + sk;
  const u16* pBh = Bh + (size_t)srow * Hh + sk;
  const u16* pBl = Bl + (size_t)srow * Hh + sk;

  f32x4 acc[2][7];
#pragma unroll
  for (int i = 0; i < 2; ++i)
#pragma unroll
    for (int j = 0; j < 7; ++j) acc[i][j] = (f32x4){0.f, 0.f, 0.f, 0.f};

  for (int k0 = 0; k0 < Hh; k0 += 32) {
    *(bf16x8*)(&Ash[srow][sk])     = *(const bf16x8*)(pAh + k0);
    *(bf16x8*)(&Ash[srow][sk + 8]) = *(const bf16x8*)(pAh + k0 + 8);
    *(bf16x8*)(&Asl[srow][sk])     = *(const bf16x8*)(pAl + k0);
    *(bf16x8*)(&Asl[srow][sk + 8]) = *(const bf16x8*)(pAl + k0 + 8);
    if (srow < PC) {
      *(bf16x8*)(&Bsh[srow][sk])     = *(const bf16x8*)(pBh + k0);
      *(bf16x8*)(&Bsh[srow][sk + 8]) = *(const bf16x8*)(pBh + k0 + 8);
      *(bf16x8*)(&Bsl[srow][sk])     = *(const bf16x8*)(pBl + k0);
      *(bf16x8*)(&Bsl[srow][sk + 8]) = *(const bf16x8*)(pBl + k0 + 8);
    }
    __syncthreads();

    bf16x8 afh[2], afl[2], bfh[7], bfl[7];
#pragma unroll
    for (int mt = 0; mt < 2; ++mt) {
      afh[mt] = *(const bf16x8*)(&Ash[wave * 32 + mt * 16 + l15][k8]);
      afl[mt] = *(const bf16x8*)(&Asl[wave * 32 + mt * 16 + l15][k8]);
    }
#pragma unroll
    for (int nt = 0; nt < 7; ++nt) {
      bfh[nt] = *(const bf16x8*)(&Bsh[nt * 16 + l15][k8]);
      bfl[nt] = *(const bf16x8*)(&Bsl[nt * 16 + l15][k8]);
    }
#pragma unroll
    for (int mt = 0; mt < 2; ++mt)
#pragma unroll
      for (int nt = 0; nt < 7; ++nt) {
        acc[mt][nt] = __builtin_amdgcn_mfma_f32_16x16x32_bf16(
            afh[mt], bfh[nt], acc[mt][nt], 0, 0, 0);
        acc[mt][nt] = __builtin_amdgcn_mfma_f32_16x16x32_bf16(
            afh[mt], bfl[nt], acc[mt][nt], 0, 0, 0);
        acc[mt][nt] = __builtin_amdgcn_mfma_f32_16x16x32_bf16(
            afl[mt], bfh[nt], acc[mt][nt], 0, 0, 0);
      }
    __syncthreads();
  }

  // per-lane bias (7 cols owned by this lane)
  float bj[7];
#pragma unroll
  for (int nt = 0; nt < 7; ++nt) {
    const int col = nt * 16 + l15;
    bj[nt] = (col < Cc) ? bout[col] : 0.f;
  }

  // fused softmax + CE: row = row0 + wave*32 + mt*16 + r4 + r (one per quad)
#pragma unroll
  for (int mt = 0; mt < 2; ++mt)
#pragma unroll
    for (int r = 0; r < 4; ++r) {
      const int row = row0 + wave * 32 + mt * 16 + r4 + r;
      float v[7];
      float mx = -INFINITY;
#pragma unroll
      for (int nt = 0; nt < 7; ++nt) {
        const int col = nt * 16 + l15;
        v[nt] = acc[mt][nt][r] + bj[nt];
        if (col < Cc) mx = fmaxf(mx, v[nt]);
      }
#pragma unroll
      for (int off = 1; off < 16; off <<= 1) mx = fmaxf(mx, __shfl_xor(mx, off));
      float e[7];
      float sum = 0.f;
#pragma unroll
      for (int nt = 0; nt < 7; ++nt) {
        const int col = nt * 16 + l15;
        e[nt] = (col < Cc) ? expf(v[nt] - mx) : 0.f;
        sum += e[nt];
      }
#pragma unroll
      for (int off = 1; off < 16; off <<= 1) sum += __shfl_xor(sum, off);
      const float inv = 1.f / sum;
#pragma unroll
      for (int nt = 0; nt < 7; ++nt) {
        const int col = nt * 16 + l15;
        if (col < Cc) preds[(size_t)row * Cc + col] = e[nt] * inv;
      }
      const int lab = labels[row];
#pragma unroll
      for (int nt = 0; nt < 7; ++nt) {
        if (nt * 16 + l15 == lab)
          ce[row] = logf(sum) + mx - v[nt];
      }
    }
}

// ---------------- SGEMM (fp32 fallback if ws too small) ----------------
#define BM 128
#define BN 128
#define BK 16

__global__ __launch_bounds__(256)
void sgemm_bias(const float* __restrict__ A, const float* __restrict__ B,
                const float* __restrict__ bias, float* __restrict__ C,
                int M, int N, int K) {
  __shared__ float As[BK][BM];
  __shared__ float Bs[BK][BN];
  const int tid  = threadIdx.x;
  const int row0 = blockIdx.y * BM, col0 = blockIdx.x * BN;
  const int tr = (tid >> 4) << 3;
  const int tc = (tid & 15) << 3;

  float acc[8][8];
#pragma unroll
  for (int i = 0; i < 8; ++i)
#pragma unroll
    for (int j = 0; j < 8; ++j) acc[i][j] = 0.f;

  const int arow = tid >> 1;
  const int acol = (tid & 1) << 3;
  const int brow = tid >> 4;
  const int bcol = (tid & 15) << 3;
  const float* Ap = A + (size_t)(row0 + arow) * K + acol;
  const float* Bp = B + (size_t)brow * N + (col0 + bcol);

  for (int k0 = 0; k0 < K; k0 += BK) {
    const float4 a0 = *(const float4*)(Ap + k0);
    const float4 a1 = *(const float4*)(Ap + k0 + 4);
    const float4 bv0 = *(const float4*)(Bp + (size_t)k0 * N);
    const float4 bv1 = *(const float4*)(Bp + (size_t)k0 * N + 4);
    As[acol + 0][arow] = a0.x;
    As[acol + 1][arow] = a0.y;
    As[acol + 2][arow] = a0.z;
    As[acol + 3][arow] = a0.w;
    As[acol + 4][arow] = a1.x;
    As[acol + 5][arow] = a1.y;
    As[acol + 6][arow] = a1.z;
    As[acol + 7][arow] = a1.w;
    *(float4*)(&Bs[brow][bcol])     = bv0;
    *(float4*)(&Bs[brow][bcol + 4]) = bv1;
    __syncthreads();
#pragma unroll
    for (int k = 0; k < BK; ++k) {
      float a[8], b[8];
      *(float4*)(a)     = *(const float4*)(&As[k][tr]);
      *(float4*)(a + 4) = *(const float4*)(&As[k][tr + 4]);
      *(float4*)(b)     = *(const float4*)(&Bs[k][tc]);
      *(float4*)(b + 4) = *(const float4*)(&Bs[k][tc + 4]);
#pragma unroll
      for (int i = 0; i < 8; ++i)
#pragma unroll
        for (int j = 0; j < 8; ++j)
          acc[i][j] = fmaf(a[i], b[j], acc[i][j]);
    }
    __syncthreads();
  }

  float bj[8];
#pragma unroll
  for (int j = 0; j < 8; ++j) bj[j] = bias[col0 + tc + j];
#pragma unroll
  for (int i = 0; i < 8; ++i) {
    float* Cp = C + (size_t)(row0 + tr + i) * N + (col0 + tc);
    float4 o0, o1;
    o0.x = acc[i][0] + bj[0]; o0.y = acc[i][1] + bj[1];
    o0.z = acc[i][2] + bj[2]; o0.w = acc[i][3] + bj[3];
    o1.x = acc[i][4] + bj[4]; o1.y = acc[i][5] + bj[5];
    o1.z = acc[i][6] + bj[6]; o1.w = acc[i][7] + bj[7];
    *(float4*)(Cp)     = o0;
    *(float4*)(Cp + 4) = o1;
  }
}

// ---------------- MFMA fused step v6: 4 blocks/CU (R16-proven layout) ---
__global__ __launch_bounds__(256, 4)
void fused_step4(const float* __restrict__ pre,
                 const u16* __restrict__ WP1h, const u16* __restrict__ WP1l,
                 const u16* __restrict__ WP2h, const u16* __restrict__ WP2l,
                 const float* __restrict__ b2,
                 u16* __restrict__ h1hi, u16* __restrict__ h1lo,
                 u16* __restrict__ h2hi, u16* __restrict__ h2lo,
                 u16* __restrict__ h2fh, u16* __restrict__ h2fl,
                 float* __restrict__ c1, float* __restrict__ c2, int t) {
  __shared__ u16 Ah[2][16][PAD128], Al[2][16][PAD128];
  __shared__ u16 Bh[2][16][PAD128], Bl[2][16][PAD128];
  __shared__ float ex[4][16][17];   // [kh][batch16][vc]
  const int tid = threadIdx.x;
  const int lane = tid & 63, kh = tid >> 6;   // wave = K-quarter
  const int fr = lane & 15, f8 = (lane >> 4) * 8, r4 = (lane >> 4) * 4;
  const bool isL2 = blockIdx.x >= 512;
  const int idx = blockIdx.x & 511;
  const int cg = idx & 127, bg = idx >> 7;    // 128 col-groups x 4 b-groups
  const int b0 = bg * 16;

  const int hr = tid >> 4, hk = (tid & 15) * 8;

  f32x4 acc = {0.f, 0.f, 0.f, 0.f};
  bool have = false;
  float p0 = 0.f, p1 = 0.f, p2 = 0.f, p3 = 0.f;

  const int eb = tid >> 2, em = tid & 3;
  const int col = cg * 4 + em;
  const int ci = (b0 + eb) * Hh + col;

  if (!isL2) {
    if (t >= Tt) return;
    if (tid < 64) {
      const float* pp = pre + ((size_t)(b0 + eb) * Tt + t) * Gg + col;
      p0 = pp[0]; p1 = pp[512]; p2 = pp[1024]; p3 = pp[1536];
    }
    if (t > 0) {
      const int sl = (t - 1) & 1;
      const u16* A_h = h1hi + (sl << 15) + (b0 + hr) * 512 + hk;
      const u16* A_l = h1lo + (sl << 15) + (b0 + hr) * 512 + hk;
      const u16* B_h = WP1h + (size_t)(cg * 16 + hr) * 512 + hk;
      const u16* B_l = WP1l + (size_t)(cg * 16 + hr) * 512 + hk;

      bf16x8 ra, rl_, rbh, rbl;
      ra = *(const bf16x8*)(A_h);   rl_ = *(const bf16x8*)(A_l);
      rbh = *(const bf16x8*)(B_h);  rbl = *(const bf16x8*)(B_l);
      *(bf16x8*)&Ah[0][hr][hk] = ra;   *(bf16x8*)&Al[0][hr][hk] = rl_;
      *(bf16x8*)&Bh[0][hr][hk] = rbh;  *(bf16x8*)&Bl[0][hr][hk] = rbl;
      __syncthreads();

      for (int kc = 0; kc < 4; ++kc) {
        const int cur = kc & 1;
        if (kc < 3) {
          const int ko = (kc + 1) * 128;
          ra = *(const bf16x8*)(A_h + ko);   rl_ = *(const bf16x8*)(A_l + ko);
          rbh = *(const bf16x8*)(B_h + ko);  rbl = *(const bf16x8*)(B_l + ko);
        }
        {
          const int c0 = kh * 32 + f8;
          const bf16x8 afh = *(const bf16x8*)&Ah[cur][fr][c0];
          const bf16x8 afl = *(const bf16x8*)&Al[cur][fr][c0];
          const bf16x8 bfh = *(const bf16x8*)&Bh[cur][fr][c0];
          const bf16x8 bfl = *(const bf16x8*)&Bl[cur][fr][c0];
          acc = __builtin_amdgcn_mfma_f32_16x16x32_bf16(afh, bfh, acc, 0, 0, 0);
          acc = __builtin_amdgcn_mfma_f32_16x16x32_bf16(afh, bfl, acc, 0, 0, 0);
          acc = __builtin_amdgcn_mfma_f32_16x16x32_bf16(afl, bfh, acc, 0, 0, 0);
        }
        if (kc < 3) {
          const int nb = cur ^ 1;
          *(bf16x8*)&Ah[nb][hr][hk] = ra;   *(bf16x8*)&Al[nb][hr][hk] = rl_;
          *(bf16x8*)&Bh[nb][hr][hk] = rbh;  *(bf16x8*)&Bl[nb][hr][hk] = rbl;
        }
        __syncthreads();
      }
      have = true;
    }
  } else {
    if (t < 1) return;
    const u16* A1h = h1hi + (((t - 1) & 1) << 15) + (b0 + hr) * 512 + hk;
    const u16* A1l = h1lo + (((t - 1) & 1) << 15) + (b0 + hr) * 512 + hk;
    const u16* A2h = h2hi + (((t - 2) & 1) << 15) + (b0 + hr) * 512 + hk;
    const u16* A2l = h2lo + (((t - 2) & 1) << 15) + (b0 + hr) * 512 + hk;
    const u16* B_h = WP2h + (size_t)(cg * 16 + hr) * 1024 + hk;
    const u16* B_l = WP2l + (size_t)(cg * 16 + hr) * 1024 + hk;
    const bool h2ok = (t >= 2);

    bf16x8 ra, rl_, rbh, rbl;
    ra = *(const bf16x8*)(A1h);   rl_ = *(const bf16x8*)(A1l);
    rbh = *(const bf16x8*)(B_h);  rbl = *(const bf16x8*)(B_l);
    *(bf16x8*)&Ah[0][hr][hk] = ra;   *(bf16x8*)&Al[0][hr][hk] = rl_;
    *(bf16x8*)&Bh[0][hr][hk] = rbh;  *(bf16x8*)&Bl[0][hr][hk] = rbl;
    __syncthreads();

    for (int kc = 0; kc < 8; ++kc) {
      const int cur = kc & 1;
      if (kc < 7) {
        const int nk = kc + 1;
        const u16* sh  = (nk < 4) ? A1h : A2h;
        const u16* sl2 = (nk < 4) ? A1l : A2l;
        const int ko = (nk & 3) * 128;
        ra = *(const bf16x8*)(sh + ko);    rl_ = *(const bf16x8*)(sl2 + ko);
        rbh = *(const bf16x8*)(B_h + nk * 128);
        rbl = *(const bf16x8*)(B_l + nk * 128);
      }
      if (kc < 4 || h2ok) {
        const int c0 = kh * 32 + f8;
        const bf16x8 afh = *(const bf16x8*)&Ah[cur][fr][c0];
        const bf16x8 afl = *(const bf16x8*)&Al[cur][fr][c0];
        const bf16x8 bfh = *(const bf16x8*)&Bh[cur][fr][c0];
        const bf16x8 bfl = *(const bf16x8*)&Bl[cur][fr][c0];
        acc = __builtin_amdgcn_mfma_f32_16x16x32_bf16(afh, bfh, acc, 0, 0, 0);
        acc = __builtin_amdgcn_mfma_f32_16x16x32_bf16(afh, bfl, acc, 0, 0, 0);
        acc = __builtin_amdgcn_mfma_f32_16x16x32_bf16(afl, bfh, acc, 0, 0, 0);
      }
      if (kc < 7) {
        const int nb = cur ^ 1;
        *(bf16x8*)&Ah[nb][hr][hk] = ra;   *(bf16x8*)&Al[nb][hr][hk] = rl_;
        *(bf16x8*)&Bh[nb][hr][hk] = rbh;  *(bf16x8*)&Bl[nb][hr][hk] = rbl;
      }
      __syncthreads();
    }
    have = true;
  }

  if (have) {
#pragma unroll
    for (int r = 0; r < 4; ++r)
      ex[kh][r4 + r][fr] = acc[r];
  }
  __syncthreads();

  if (tid < 64) {
    float s0 = 0.f, s1 = 0.f, s2 = 0.f, s3 = 0.f;
    if (have) {
#pragma unroll
      for (int q = 0; q < 4; ++q) {
        s0 += ex[q][eb][0 + em];
        s1 += ex[q][eb][4 + em];
        s2 += ex[q][eb][8 + em];
        s3 += ex[q][eb][12 + em];
      }
    }
    if (!isL2) {
      const float gi = p0 + s0, gj = p1 + s1, gf = p2 + s2, go = p3 + s3;
      const float cp = (t > 0) ? c1[ci] : 0.f;
      const float nc = fmaf(cp, sigm(gf + 1.f), sigm(gi) * tanhf(gj));
      c1[ci] = nc;
      const float nh = tanhf(nc) * sigm(go);
      u16 hh, hl;
      split_bf16(nh, hh, hl);
      const int hidx = ((t & 1) << 15) + ci;
      h1hi[hidx] = hh;
      h1lo[hidx] = hl;
    } else {
      const float gi = b2[col] + s0, gj = b2[512 + col] + s1;
      const float gf = b2[1024 + col] + s2, go = b2[1536 + col] + s3;
      const float cp = (t >= 2) ? c2[ci] : 0.f;
      const float nc = fmaf(cp, sigm(gf + 1.f), sigm(gi) * tanhf(gj));
      c2[ci] = nc;
      const float nh = tanhf(nc) * sigm(go);
      u16 hh, hl;
      split_bf16(nh, hh, hl);
      const int hidx = (((t - 1) & 1) << 15) + ci;
      h2hi[hidx] = hh;
      h2lo[hidx] = hl;
      const size_t fo = ((size_t)(b0 + eb) * Tt + (t - 1)) * Hh + col;
      h2fh[fo] = hh;
      h2fl[fo] = hl;
    }
  }
}

__global__ __launch_bounds__(256)
void reduce_cost(const float* __restrict__ ce, float* __restrict__ out) {
  __shared__ float red[256];
  const int tid = threadIdx.x;
  float s = 0.f;
  for (int i = tid; i < ROWS; i += 256) s += ce[i];
  red[tid] = s;
  __syncthreads();
  for (int st = 128; st > 0; st >>= 1) {
    if (tid < st) red[tid] += red[tid + st];
    __syncthreads();
  }
  if (tid == 0) out[0] = red[0] / (float)Bb;
}

// ---------------- launch ----------------
extern "C" void kernel_launch(void* const* d_in, const int* in_sizes, int n_in,
                              void* d_out, int out_size, void* d_ws, size_t ws_size,
                              hipStream_t stream) {
  const float* inputs = (const float*)d_in[0];
  const int*   labels = (const int*)d_in[1];
  const float* W1     = (const float*)d_in[2];
  const float* b1     = (const float*)d_in[3];
  const float* W2     = (const float*)d_in[4];
  const float* b2     = (const float*)d_in[5];
  const float* Wout   = (const float*)d_in[6];
  const float* bout   = (const float*)d_in[7];
  float* out = (float*)d_out;

  float* ws     = (float*)d_ws;
  float* pre    = ws;                              // ROWS*Gg   (16M f32)
  float* c1     = pre    + (size_t)ROWS * Gg;      // 64*512
  float* c2     = c1     + (size_t)Bb * Hh;
  float* ceb    = c2     + (size_t)Bb * Hh;        // ROWS
  u16* h1hi = (u16*)(ceb + ROWS);                  // [2][64][512]
  u16* h1lo = h1hi + 2 * 64 * 512;
  u16* h2hi = h1lo + 2 * 64 * 512;
  u16* h2lo = h2hi + 2 * 64 * 512;
  u16* h2fh = h2lo + 2 * 64 * 512;                 // ROWS*Hh
  u16* h2fl = h2fh + (size_t)ROWS * Hh;
  u16* WP1h = h2fl + (size_t)ROWS * Hh;            // 128*16*512
  u16* WP1l = WP1h + 128 * 16 * 512;
  u16* WP2h = WP1l + 128 * 16 * 512;               // 128*16*1024
  u16* WP2l = WP2h + 128 * 16 * 1024;
  u16* WoTh = WP2l + 128 * 16 * 1024;              // PC*Hh
  u16* WoTl = WoTh + PC * Hh;
  u16* Xhi  = WoTl + PC * Hh;                      // ROWS*Dd
  u16* Xlo  = Xhi  + (size_t)ROWS * Dd;
  u16* W1Th = Xlo  + (size_t)ROWS * Dd;            // Gg*Dd
  u16* W1Tl = W1Th + (size_t)Gg * Dd;
  const size_t need = (size_t)((char*)(W1Tl + (size_t)Gg * Dd) - (char*)d_ws);
  const bool use_mfma = ws_size >= need;

  // weights: permute+split once
  permuteW<<<dim3(16, 64), dim3(32, 8), 0, stream>>>(
      W1 + (size_t)Dd * Gg, WP1h, WP1l, 512);
  permuteW<<<dim3(32, 64), dim3(32, 8), 0, stream>>>(W2, WP2h, WP2l, 1024);
  convert_woutT<<<PC, 256, 0, stream>>>(Wout, WoTh, WoTl);

  // Layer 1 input projection: pre = X @ W1[0:D,:] + b1
  if (use_mfma) {
    convert_hilo<<<2048, 256, 0, stream>>>(inputs, Xhi, Xlo, ROWS * Dd / 4);
    convertT_w1<<<dim3(64, 64), dim3(32, 8), 0, stream>>>(W1, W1Th, W1Tl);
    gemm1_mfma<<<1024, 256, 0, stream>>>(Xhi, Xlo, W1Th, W1Tl, b1, pre);
  } else {
    sgemm_bias<<<dim3(Gg / BN, ROWS / BM), dim3(256), 0, stream>>>(
        inputs, W1, b1, pre, ROWS, Gg, Dd);
  }

  // Recurrence: phase t = L1 step t (blocks 0..511) + L2 step t-1 (512..1023)
  for (int t = 0; t <= Tt; ++t)
    fused_step4<<<1024, 256, 0, stream>>>(pre, WP1h, WP1l, WP2h, WP2l, b2,
                                          h1hi, h1lo, h2hi, h2lo,
                                          h2fh, h2fl, c1, c2, t);

  // Output projection with fused softmax/CE, then cost reduction
  gemm_proj<<<ROWS / 128, 256, 0, stream>>>(h2fh, h2fl, WoTh, WoTl, bout,
                                            labels, out, ceb);
  reduce_cost<<<1, 256, 0, stream>>>(ceb, out + (size_t)ROWS * Cc);
}

// Round 20
// 1480.590 us; speedup vs baseline: 1.1887x; 1.0111x over previous
//
#include <hip/hip_runtime.h>
#include <cmath>

// Problem constants
#define Bb   64
#define Tt   128
#define Dd   2048
#define Hh   512
#define Gg   2048      // 4*H
#define Cc   101
#define PC   112       // classes padded to 7*16 for MFMA
#define ROWS 8192      // B*T

typedef unsigned short u16;
typedef __attribute__((ext_vector_type(8))) short bf16x8;
typedef __attribute__((ext_vector_type(4))) float f32x4;

#define PAD32 40
#define PAD128 136

// global -> LDS direct (async DMA, width 16B). LDS dest must be linear in
// lane order (m104): wave-uniform base + lane*16. Source is per-lane.
#define GLOAD_LDS16(g, l) __builtin_amdgcn_global_load_lds(                  \
    (const __attribute__((address_space(1))) unsigned int*)(const void*)(g), \
    (__attribute__((address_space(3))) unsigned int*)(void*)(l), 16, 0, 0)

// ---------------- bf16 hi/lo split helpers ----------------
__device__ __forceinline__ u16 bf16rne(float x) {
  unsigned u = __float_as_uint(x);
  unsigned r = (u + 0x7fffu + ((u >> 16) & 1u)) >> 16;
  return (u16)r;
}
__device__ __forceinline__ void split_bf16(float x, u16& h, u16& l) {
  h = bf16rne(x);
  l = bf16rne(x - __uint_as_float(((unsigned)h) << 16));
}
__device__ __forceinline__ float sigm(float x) { return 1.f / (1.f + expf(-x)); }

// X [ROWS x Dd] fp32 -> Xhi, Xlo bf16 (same layout)
__global__ __launch_bounds__(256)
void convert_hilo(const float* __restrict__ src, u16* __restrict__ hi,
                  u16* __restrict__ lo, int n4) {
  for (int i = blockIdx.x * 256 + threadIdx.x; i < n4; i += gridDim.x * 256) {
    const float4 v = ((const float4*)src)[i];
    ushort4 h, l;
    split_bf16(v.x, h.x, l.x);
    split_bf16(v.y, h.y, l.y);
    split_bf16(v.z, h.z, l.z);
    split_bf16(v.w, h.w, l.w);
    ((ushort4*)hi)[i] = h;
    ((ushort4*)lo)[i] = l;
  }
}

// W1 top [Dd x Gg] -> W1T hi/lo [Gg x Dd] bf16  (for gemm1 B operand)
__global__ __launch_bounds__(256)
void convertT_w1(const float* __restrict__ W1, u16* __restrict__ Th,
                 u16* __restrict__ Tl) {
  __shared__ float tl[32][33];
  const int tx = threadIdx.x, ty = threadIdx.y;   // 32, 8
  const int k0 = blockIdx.x * 32, c0 = blockIdx.y * 32;
#pragma unroll
  for (int j = 0; j < 4; ++j)
    tl[ty + j * 8][tx] = W1[(size_t)(k0 + ty + j * 8) * Gg + (c0 + tx)];
  __syncthreads();
#pragma unroll
  for (int j = 0; j < 4; ++j) {
    const float v = tl[tx][ty + j * 8];
    u16 h, l;
    split_bf16(v, h, l);
    const size_t o = (size_t)(c0 + ty + j * 8) * Dd + (k0 + tx);
    Th[o] = h;
    Tl[o] = l;
  }
}

// Wout [Hh x Cc] -> WoutT hi/lo [PC x Hh] (rows >= Cc zero)
__global__ __launch_bounds__(256)
void convert_woutT(const float* __restrict__ Wout, u16* __restrict__ Th,
                   u16* __restrict__ Tl) {
  const int c = blockIdx.x;
  for (int k = threadIdx.x; k < Hh; k += 256) {
    const float v = (c < Cc) ? Wout[k * Cc + c] : 0.f;
    u16 h, l;
    split_bf16(v, h, l);
    Th[c * Hh + k] = h;
    Tl[c * Hh + k] = l;
  }
}

// Recurrent weights, permuted + split:
// WP[cg 128][vc 16][K], vc = g*4 + m for col = g*512 + cg*4 + m.
__global__ __launch_bounds__(256)
void permuteW(const float* __restrict__ src, u16* __restrict__ dh,
              u16* __restrict__ dl, int K) {
  __shared__ float tl[32][33];
  const int tx = threadIdx.x, ty = threadIdx.y;   // 32, 8
  const int k0 = blockIdx.x * 32, c0 = blockIdx.y * 32;
#pragma unroll
  for (int j = 0; j < 4; ++j)
    tl[ty + j * 8][tx] = src[(size_t)(k0 + ty + j * 8) * Gg + (c0 + tx)];
  __syncthreads();
#pragma unroll
  for (int j = 0; j < 4; ++j) {
    const int col = c0 + ty + j * 8;
    const int g = col >> 9, mg = col & 511;
    const int cg = mg >> 2, m = mg & 3;
    const float v = tl[tx][ty + j * 8];
    u16 h, l;
    split_bf16(v, h, l);
    const size_t o = (size_t)(cg * 16 + g * 4 + m) * K + k0 + tx;
    dh[o] = h;
    dl[o] = l;
  }
}

// ---------------- MFMA bf16x3 GEMM: pre = X @ W1 + b1 ----------------
// Staging via global_load_lds width=16 (m97-ladder step: +35% over
// reg-staging at 128^2 tiles). LDS linear [128][32]; thread tid owns LDS
// bytes tid*16 (row tid/4, col (tid&3)*8) and +4KB half (row +64).
// Frag-read bank conflicts (3.35e7) measured harmless across 3 layouts.
__global__ __launch_bounds__(256)
void gemm1_mfma(const u16* __restrict__ Ah, const u16* __restrict__ Al,
                const u16* __restrict__ Bh, const u16* __restrict__ Bl,
                const float* __restrict__ bias, float* __restrict__ C) {
  __shared__ u16 Ash[128][32];
  __shared__ u16 Asl[128][32];
  __shared__ u16 Bsh[128][32];
  __shared__ u16 Bsl[128][32];
  const int tid  = threadIdx.x;
  const int lane = tid & 63, wave = tid >> 6;
  const int wm = wave >> 1, wn = wave & 1;
  const int l15 = lane & 15, q = lane >> 4, r4 = (lane >> 4) * 4;
  const int lin = blockIdx.x;
  const int xcd = lin & 7, s = lin >> 3;
  const int bx = 2 * xcd + (s & 1);     // col-block 0..15
  const int by = s >> 1;                // row-block 0..63
  const int row0 = by * 128, col0 = bx * 128;

  // staging map: row sr / sr+64, col sc (8 u16 = 16B per call)
  const int sr = tid >> 2, sc = (tid & 3) * 8;
  const u16* gA0h = Ah + (size_t)(row0 + sr) * Dd + sc;
  const u16* gA1h = Ah + (size_t)(row0 + 64 + sr) * Dd + sc;
  const u16* gA0l = Al + (size_t)(row0 + sr) * Dd + sc;
  const u16* gA1l = Al + (size_t)(row0 + 64 + sr) * Dd + sc;
  const u16* gB0h = Bh + (size_t)(col0 + sr) * Dd + sc;
  const u16* gB1h = Bh + (size_t)(col0 + 64 + sr) * Dd + sc;
  const u16* gB0l = Bl + (size_t)(col0 + sr) * Dd + sc;
  const u16* gB1l = Bl + (size_t)(col0 + 64 + sr) * Dd + sc;
  u16* lA0h = &Ash[sr][sc];      u16* lA1h = &Ash[64 + sr][sc];
  u16* lA0l = &Asl[sr][sc];      u16* lA1l = &Asl[64 + sr][sc];
  u16* lB0h = &Bsh[sr][sc];      u16* lB1h = &Bsh[64 + sr][sc];
  u16* lB0l = &Bsl[sr][sc];      u16* lB1l = &Bsl[64 + sr][sc];

  f32x4 acc[4][4];
#pragma unroll
  for (int i = 0; i < 4; ++i)
#pragma unroll
    for (int j = 0; j < 4; ++j) acc[i][j] = (f32x4){0.f, 0.f, 0.f, 0.f};

  for (int k0 = 0; k0 < Dd; k0 += 32) {
    GLOAD_LDS16(gA0h + k0, lA0h);
    GLOAD_LDS16(gA1h + k0, lA1h);
    GLOAD_LDS16(gA0l + k0, lA0l);
    GLOAD_LDS16(gA1l + k0, lA1l);
    GLOAD_LDS16(gB0h + k0, lB0h);
    GLOAD_LDS16(gB1h + k0, lB1h);
    GLOAD_LDS16(gB0l + k0, lB0l);
    GLOAD_LDS16(gB1l + k0, lB1l);
    __syncthreads();

    bf16x8 afh[4], afl[4], bfh[4], bfl[4];
#pragma unroll
    for (int mt = 0; mt < 4; ++mt) {
      const int row = wm * 64 + mt * 16 + l15;
      afh[mt] = *(const bf16x8*)(&Ash[row][q * 8]);
      afl[mt] = *(const bf16x8*)(&Asl[row][q * 8]);
    }
#pragma unroll
    for (int nt = 0; nt < 4; ++nt) {
      const int row = wn * 64 + nt * 16 + l15;
      bfh[nt] = *(const bf16x8*)(&Bsh[row][q * 8]);
      bfl[nt] = *(const bf16x8*)(&Bsl[row][q * 8]);
    }
#pragma unroll
    for (int mt = 0; mt < 4; ++mt)
#pragma unroll
      for (int nt = 0; nt < 4; ++nt) {
        acc[mt][nt] = __builtin_amdgcn_mfma_f32_16x16x32_bf16(
            afh[mt], bfh[nt], acc[mt][nt], 0, 0, 0);
        acc[mt][nt] = __builtin_amdgcn_mfma_f32_16x16x32_bf16(
            afh[mt], bfl[nt], acc[mt][nt], 0, 0, 0);
        acc[mt][nt] = __builtin_amdgcn_mfma_f32_16x16x32_bf16(
            afl[mt], bfh[nt], acc[mt][nt], 0, 0, 0);
      }
    __syncthreads();
  }

#pragma unroll
  for (int nt = 0; nt < 4; ++nt) {
    const int col = col0 + wn * 64 + nt * 16 + l15;
    const float bj = bias[col];
#pragma unroll
    for (int mt = 0; mt < 4; ++mt) {
      float* Cp = C + (size_t)(row0 + wm * 64 + mt * 16 + r4) * Gg + col;
#pragma unroll
      for (int r = 0; r < 4; ++r)
        Cp[(size_t)r * Gg] = acc[mt][nt][r] + bj;
    }
  }
}

// ---------------- MFMA proj + fused softmax/CE ----------------
__global__ __launch_bounds__(256)
void gemm_proj(const u16* __restrict__ Ah, const u16* __restrict__ Al,
               const u16* __restrict__ Bh, const u16* __restrict__ Bl,
               const float* __restrict__ bout, const int* __restrict__ labels,
               float* __restrict__ preds, float* __restrict__ ce) {
  __shared__ u16 Ash[128][PAD32];
  __shared__ u16 Asl[128][PAD32];
  __shared__ u16 Bsh[PC][PAD32];
  __shared__ u16 Bsl[PC][PAD32];
  const int tid  = threadIdx.x;
  const int lane = tid & 63, wave = tid >> 6;
  const int l15 = lane & 15, k8 = (lane >> 4) * 8, r4 = (lane >> 4) * 4;
  const int row0 = blockIdx.x * 128;
  const int srow = tid >> 1, sk = (tid & 1) * 16;

  const u16* pAh = Ah + (size_t)(row0 + srow) * Hh + sk;
  const u16* pAl = Al + (size_t)(row0 + srow) * Hh + sk;
  const u16* pBh = Bh + (size_t)srow * Hh + sk;
  const u16* pBl = Bl + (size_t)srow * Hh + sk;

  f32x4 acc[2][7];
#pragma unroll
  for (int i = 0; i < 2; ++i)
#pragma unroll
    for (int j = 0; j < 7; ++j) acc[i][j] = (f32x4){0.f, 0.f, 0.f, 0.f};

  for (int k0 = 0; k0 < Hh; k0 += 32) {
    *(bf16x8*)(&Ash[srow][sk])     = *(const bf16x8*)(pAh + k0);
    *(bf16x8*)(&Ash[srow][sk + 8]) = *(const bf16x8*)(pAh + k0 + 8);
    *(bf16x8*)(&Asl[srow][sk])     = *(const bf16x8*)(pAl + k0);
    *(bf16x8*)(&Asl[srow][sk + 8]) = *(const bf16x8*)(pAl + k0 + 8);
    if (srow < PC) {
      *(bf16x8*)(&Bsh[srow][sk])     = *(const bf16x8*)(pBh + k0);
      *(bf16x8*)(&Bsh[srow][sk + 8]) = *(const bf16x8*)(pBh + k0 + 8);
      *(bf16x8*)(&Bsl[srow][sk])     = *(const bf16x8*)(pBl + k0);
      *(bf16x8*)(&Bsl[srow][sk + 8]) = *(const bf16x8*)(pBl + k0 + 8);
    }
    __syncthreads();

    bf16x8 afh[2], afl[2], bfh[7], bfl[7];
#pragma unroll
    for (int mt = 0; mt < 2; ++mt) {
      afh[mt] = *(const bf16x8*)(&Ash[wave * 32 + mt * 16 + l15][k8]);
      afl[mt] = *(const bf16x8*)(&Asl[wave * 32 + mt * 16 + l15][k8]);
    }
#pragma unroll
    for (int nt = 0; nt < 7; ++nt) {
      bfh[nt] = *(const bf16x8*)(&Bsh[nt * 16 + l15][k8]);
      bfl[nt] = *(const bf16x8*)(&Bsl[nt * 16 + l15][k8]);
    }
#pragma unroll
    for (int mt = 0; mt < 2; ++mt)
#pragma unroll
      for (int nt = 0; nt < 7; ++nt) {
        acc[mt][nt] = __builtin_amdgcn_mfma_f32_16x16x32_bf16(
            afh[mt], bfh[nt], acc[mt][nt], 0, 0, 0);
        acc[mt][nt] = __builtin_amdgcn_mfma_f32_16x16x32_bf16(
            afh[mt], bfl[nt], acc[mt][nt], 0, 0, 0);
        acc[mt][nt] = __builtin_amdgcn_mfma_f32_16x16x32_bf16(
            afl[mt], bfh[nt], acc[mt][nt], 0, 0, 0);
      }
    __syncthreads();
  }

  float bj[7];
#pragma unroll
  for (int nt = 0; nt < 7; ++nt) {
    const int col = nt * 16 + l15;
    bj[nt] = (col < Cc) ? bout[col] : 0.f;
  }

#pragma unroll
  for (int mt = 0; mt < 2; ++mt)
#pragma unroll
    for (int r = 0; r < 4; ++r) {
      const int row = row0 + wave * 32 + mt * 16 + r4 + r;
      float v[7];
      float mx = -INFINITY;
#pragma unroll
      for (int nt = 0; nt < 7; ++nt) {
        const int col = nt * 16 + l15;
        v[nt] = acc[mt][nt][r] + bj[nt];
        if (col < Cc) mx = fmaxf(mx, v[nt]);
      }
#pragma unroll
      for (int off = 1; off < 16; off <<= 1) mx = fmaxf(mx, __shfl_xor(mx, off));
      float e[7];
      float sum = 0.f;
#pragma unroll
      for (int nt = 0; nt < 7; ++nt) {
        const int col = nt * 16 + l15;
        e[nt] = (col < Cc) ? expf(v[nt] - mx) : 0.f;
        sum += e[nt];
      }
#pragma unroll
      for (int off = 1; off < 16; off <<= 1) sum += __shfl_xor(sum, off);
      const float inv = 1.f / sum;
#pragma unroll
      for (int nt = 0; nt < 7; ++nt) {
        const int col = nt * 16 + l15;
        if (col < Cc) preds[(size_t)row * Cc + col] = e[nt] * inv;
      }
      const int lab = labels[row];
#pragma unroll
      for (int nt = 0; nt < 7; ++nt) {
        if (nt * 16 + l15 == lab)
          ce[row] = logf(sum) + mx - v[nt];
      }
    }
}

// ---------------- SGEMM (fp32 fallback if ws too small) ----------------
#define BM 128
#define BN 128
#define BK 16

__global__ __launch_bounds__(256)
void sgemm_bias(const float* __restrict__ A, const float* __restrict__ B,
                const float* __restrict__ bias, float* __restrict__ C,
                int M, int N, int K) {
  __shared__ float As[BK][BM];
  __shared__ float Bs[BK][BN];
  const int tid  = threadIdx.x;
  const int row0 = blockIdx.y * BM, col0 = blockIdx.x * BN;
  const int tr = (tid >> 4) << 3;
  const int tc = (tid & 15) << 3;

  float acc[8][8];
#pragma unroll
  for (int i = 0; i < 8; ++i)
#pragma unroll
    for (int j = 0; j < 8; ++j) acc[i][j] = 0.f;

  const int arow = tid >> 1;
  const int acol = (tid & 1) << 3;
  const int brow = tid >> 4;
  const int bcol = (tid & 15) << 3;
  const float* Ap = A + (size_t)(row0 + arow) * K + acol;
  const float* Bp = B + (size_t)brow * N + (col0 + bcol);

  for (int k0 = 0; k0 < K; k0 += BK) {
    const float4 a0 = *(const float4*)(Ap + k0);
    const float4 a1 = *(const float4*)(Ap + k0 + 4);
    const float4 bv0 = *(const float4*)(Bp + (size_t)k0 * N);
    const float4 bv1 = *(const float4*)(Bp + (size_t)k0 * N + 4);
    As[acol + 0][arow] = a0.x;
    As[acol + 1][arow] = a0.y;
    As[acol + 2][arow] = a0.z;
    As[acol + 3][arow] = a0.w;
    As[acol + 4][arow] = a1.x;
    As[acol + 5][arow] = a1.y;
    As[acol + 6][arow] = a1.z;
    As[acol + 7][arow] = a1.w;
    *(float4*)(&Bs[brow][bcol])     = bv0;
    *(float4*)(&Bs[brow][bcol + 4]) = bv1;
    __syncthreads();
#pragma unroll
    for (int k = 0; k < BK; ++k) {
      float a[8], b[8];
      *(float4*)(a)     = *(const float4*)(&As[k][tr]);
      *(float4*)(a + 4) = *(const float4*)(&As[k][tr + 4]);
      *(float4*)(b)     = *(const float4*)(&Bs[k][tc]);
      *(float4*)(b + 4) = *(const float4*)(&Bs[k][tc + 4]);
#pragma unroll
      for (int i = 0; i < 8; ++i)
#pragma unroll
        for (int j = 0; j < 8; ++j)
          acc[i][j] = fmaf(a[i], b[j], acc[i][j]);
    }
    __syncthreads();
  }

  float bj[8];
#pragma unroll
  for (int j = 0; j < 8; ++j) bj[j] = bias[col0 + tc + j];
#pragma unroll
  for (int i = 0; i < 8; ++i) {
    float* Cp = C + (size_t)(row0 + tr + i) * N + (col0 + tc);
    float4 o0, o1;
    o0.x = acc[i][0] + bj[0]; o0.y = acc[i][1] + bj[1];
    o0.z = acc[i][2] + bj[2]; o0.w = acc[i][3] + bj[3];
    o1.x = acc[i][4] + bj[4]; o1.y = acc[i][5] + bj[5];
    o1.z = acc[i][6] + bj[6]; o1.w = acc[i][7] + bj[7];
    *(float4*)(Cp)     = o0;
    *(float4*)(Cp + 4) = o1;
  }
}

// ---------------- MFMA fused step v6: 4 blocks/CU (R16-proven layout) ---
__global__ __launch_bounds__(256, 4)
void fused_step4(const float* __restrict__ pre,
                 const u16* __restrict__ WP1h, const u16* __restrict__ WP1l,
                 const u16* __restrict__ WP2h, const u16* __restrict__ WP2l,
                 const float* __restrict__ b2,
                 u16* __restrict__ h1hi, u16* __restrict__ h1lo,
                 u16* __restrict__ h2hi, u16* __restrict__ h2lo,
                 u16* __restrict__ h2fh, u16* __restrict__ h2fl,
                 float* __restrict__ c1, float* __restrict__ c2, int t) {
  __shared__ u16 Ah[2][16][PAD128], Al[2][16][PAD128];
  __shared__ u16 Bh[2][16][PAD128], Bl[2][16][PAD128];
  __shared__ float ex[4][16][17];   // [kh][batch16][vc]
  const int tid = threadIdx.x;
  const int lane = tid & 63, kh = tid >> 6;   // wave = K-quarter
  const int fr = lane & 15, f8 = (lane >> 4) * 8, r4 = (lane >> 4) * 4;
  const bool isL2 = blockIdx.x >= 512;
  const int idx = blockIdx.x & 511;
  const int cg = idx & 127, bg = idx >> 7;    // 128 col-groups x 4 b-groups
  const int b0 = bg * 16;

  const int hr = tid >> 4, hk = (tid & 15) * 8;

  f32x4 acc = {0.f, 0.f, 0.f, 0.f};
  bool have = false;
  float p0 = 0.f, p1 = 0.f, p2 = 0.f, p3 = 0.f;

  const int eb = tid >> 2, em = tid & 3;
  const int col = cg * 4 + em;
  const int ci = (b0 + eb) * Hh + col;

  if (!isL2) {
    if (t >= Tt) return;
    if (tid < 64) {
      const float* pp = pre + ((size_t)(b0 + eb) * Tt + t) * Gg + col;
      p0 = pp[0]; p1 = pp[512]; p2 = pp[1024]; p3 = pp[1536];
    }
    if (t > 0) {
      const int sl = (t - 1) & 1;
      const u16* A_h = h1hi + (sl << 15) + (b0 + hr) * 512 + hk;
      const u16* A_l = h1lo + (sl << 15) + (b0 + hr) * 512 + hk;
      const u16* B_h = WP1h + (size_t)(cg * 16 + hr) * 512 + hk;
      const u16* B_l = WP1l + (size_t)(cg * 16 + hr) * 512 + hk;

      bf16x8 ra, rl_, rbh, rbl;
      ra = *(const bf16x8*)(A_h);   rl_ = *(const bf16x8*)(A_l);
      rbh = *(const bf16x8*)(B_h);  rbl = *(const bf16x8*)(B_l);
      *(bf16x8*)&Ah[0][hr][hk] = ra;   *(bf16x8*)&Al[0][hr][hk] = rl_;
      *(bf16x8*)&Bh[0][hr][hk] = rbh;  *(bf16x8*)&Bl[0][hr][hk] = rbl;
      __syncthreads();

      for (int kc = 0; kc < 4; ++kc) {
        const int cur = kc & 1;
        if (kc < 3) {
          const int ko = (kc + 1) * 128;
          ra = *(const bf16x8*)(A_h + ko);   rl_ = *(const bf16x8*)(A_l + ko);
          rbh = *(const bf16x8*)(B_h + ko);  rbl = *(const bf16x8*)(B_l + ko);
        }
        {
          const int c0 = kh * 32 + f8;
          const bf16x8 afh = *(const bf16x8*)&Ah[cur][fr][c0];
          const bf16x8 afl = *(const bf16x8*)&Al[cur][fr][c0];
          const bf16x8 bfh = *(const bf16x8*)&Bh[cur][fr][c0];
          const bf16x8 bfl = *(const bf16x8*)&Bl[cur][fr][c0];
          acc = __builtin_amdgcn_mfma_f32_16x16x32_bf16(afh, bfh, acc, 0, 0, 0);
          acc = __builtin_amdgcn_mfma_f32_16x16x32_bf16(afh, bfl, acc, 0, 0, 0);
          acc = __builtin_amdgcn_mfma_f32_16x16x32_bf16(afl, bfh, acc, 0, 0, 0);
        }
        if (kc < 3) {
          const int nb = cur ^ 1;
          *(bf16x8*)&Ah[nb][hr][hk] = ra;   *(bf16x8*)&Al[nb][hr][hk] = rl_;
          *(bf16x8*)&Bh[nb][hr][hk] = rbh;  *(bf16x8*)&Bl[nb][hr][hk] = rbl;
        }
        __syncthreads();
      }
      have = true;
    }
  } else {
    if (t < 1) return;
    const u16* A1h = h1hi + (((t - 1) & 1) << 15) + (b0 + hr) * 512 + hk;
    const u16* A1l = h1lo + (((t - 1) & 1) << 15) + (b0 + hr) * 512 + hk;
    const u16* A2h = h2hi + (((t - 2) & 1) << 15) + (b0 + hr) * 512 + hk;
    const u16* A2l = h2lo + (((t - 2) & 1) << 15) + (b0 + hr) * 512 + hk;
    const u16* B_h = WP2h + (size_t)(cg * 16 + hr) * 1024 + hk;
    const u16* B_l = WP2l + (size_t)(cg * 16 + hr) * 1024 + hk;
    const bool h2ok = (t >= 2);

    bf16x8 ra, rl_, rbh, rbl;
    ra = *(const bf16x8*)(A1h);   rl_ = *(const bf16x8*)(A1l);
    rbh = *(const bf16x8*)(B_h);  rbl = *(const bf16x8*)(B_l);
    *(bf16x8*)&Ah[0][hr][hk] = ra;   *(bf16x8*)&Al[0][hr][hk] = rl_;
    *(bf16x8*)&Bh[0][hr][hk] = rbh;  *(bf16x8*)&Bl[0][hr][hk] = rbl;
    __syncthreads();

    for (int kc = 0; kc < 8; ++kc) {
      const int cur = kc & 1;
      if (kc < 7) {
        const int nk = kc + 1;
        const u16* sh  = (nk < 4) ? A1h : A2h;
        const u16* sl2 = (nk < 4) ? A1l : A2l;
        const int ko = (nk & 3) * 128;
        ra = *(const bf16x8*)(sh + ko);    rl_ = *(const bf16x8*)(sl2 + ko);
        rbh = *(const bf16x8*)(B_h + nk * 128);
        rbl = *(const bf16x8*)(B_l + nk * 128);
      }
      if (kc < 4 || h2ok) {
        const int c0 = kh * 32 + f8;
        const bf16x8 afh = *(const bf16x8*)&Ah[cur][fr][c0];
        const bf16x8 afl = *(const bf16x8*)&Al[cur][fr][c0];
        const bf16x8 bfh = *(const bf16x8*)&Bh[cur][fr][c0];
        const bf16x8 bfl = *(const bf16x8*)&Bl[cur][fr][c0];
        acc = __builtin_amdgcn_mfma_f32_16x16x32_bf16(afh, bfh, acc, 0, 0, 0);
        acc = __builtin_amdgcn_mfma_f32_16x16x32_bf16(afh, bfl, acc, 0, 0, 0);
        acc = __builtin_amdgcn_mfma_f32_16x16x32_bf16(afl, bfh, acc, 0, 0, 0);
      }
      if (kc < 7) {
        const int nb = cur ^ 1;
        *(bf16x8*)&Ah[nb][hr][hk] = ra;   *(bf16x8*)&Al[nb][hr][hk] = rl_;
        *(bf16x8*)&Bh[nb][hr][hk] = rbh;  *(bf16x8*)&Bl[nb][hr][hk] = rbl;
      }
      __syncthreads();
    }
    have = true;
  }

  if (have) {
#pragma unroll
    for (int r = 0; r < 4; ++r)
      ex[kh][r4 + r][fr] = acc[r];
  }
  __syncthreads();

  if (tid < 64) {
    float s0 = 0.f, s1 = 0.f, s2 = 0.f, s3 = 0.f;
    if (have) {
#pragma unroll
      for (int q = 0; q < 4; ++q) {
        s0 += ex[q][eb][0 + em];
        s1 += ex[q][eb][4 + em];
        s2 += ex[q][eb][8 + em];
        s3 += ex[q][eb][12 + em];
      }
    }
    if (!isL2) {
      const float gi = p0 + s0, gj = p1 + s1, gf = p2 + s2, go = p3 + s3;
      const float cp = (t > 0) ? c1[ci] : 0.f;
      const float nc = fmaf(cp, sigm(gf + 1.f), sigm(gi) * tanhf(gj));
      c1[ci] = nc;
      const float nh = tanhf(nc) * sigm(go);
      u16 hh, hl;
      split_bf16(nh, hh, hl);
      const int hidx = ((t & 1) << 15) + ci;
      h1hi[hidx] = hh;
      h1lo[hidx] = hl;
    } else {
      const float gi = b2[col] + s0, gj = b2[512 + col] + s1;
      const float gf = b2[1024 + col] + s2, go = b2[1536 + col] + s3;
      const float cp = (t >= 2) ? c2[ci] : 0.f;
      const float nc = fmaf(cp, sigm(gf + 1.f), sigm(gi) * tanhf(gj));
      c2[ci] = nc;
      const float nh = tanhf(nc) * sigm(go);
      u16 hh, hl;
      split_bf16(nh, hh, hl);
      const int hidx = (((t - 1) & 1) << 15) + ci;
      h2hi[hidx] = hh;
      h2lo[hidx] = hl;
      const size_t fo = ((size_t)(b0 + eb) * Tt + (t - 1)) * Hh + col;
      h2fh[fo] = hh;
      h2fl[fo] = hl;
    }
  }
}

__global__ __launch_bounds__(256)
void reduce_cost(const float* __restrict__ ce, float* __restrict__ out) {
  __shared__ float red[256];
  const int tid = threadIdx.x;
  float s = 0.f;
  for (int i = tid; i < ROWS; i += 256) s += ce[i];
  red[tid] = s;
  __syncthreads();
  for (int st = 128; st > 0; st >>= 1) {
    if (tid < st) red[tid] += red[tid + st];
    __syncthreads();
  }
  if (tid == 0) out[0] = red[0] / (float)Bb;
}

// ---------------- launch ----------------
extern "C" void kernel_launch(void* const* d_in, const int* in_sizes, int n_in,
                              void* d_out, int out_size, void* d_ws, size_t ws_size,
                              hipStream_t stream) {
  const float* inputs = (const float*)d_in[0];
  const int*   labels = (const int*)d_in[1];
  const float* W1     = (const float*)d_in[2];
  const float* b1     = (const float*)d_in[3];
  const float* W2     = (const float*)d_in[4];
  const float* b2     = (const float*)d_in[5];
  const float* Wout   = (const float*)d_in[6];
  const float* bout   = (const float*)d_in[7];
  float* out = (float*)d_out;

  float* ws     = (float*)d_ws;
  float* pre    = ws;                              // ROWS*Gg   (16M f32)
  float* c1     = pre    + (size_t)ROWS * Gg;      // 64*512
  float* c2     = c1     + (size_t)Bb * Hh;
  float* ceb    = c2     + (size_t)Bb * Hh;        // ROWS
  u16* h1hi = (u16*)(ceb + ROWS);                  // [2][64][512]
  u16* h1lo = h1hi + 2 * 64 * 512;
  u16* h2hi = h1lo + 2 * 64 * 512;
  u16* h2lo = h2hi + 2 * 64 * 512;
  u16* h2fh = h2lo + 2 * 64 * 512;                 // ROWS*Hh
  u16* h2fl = h2fh + (size_t)ROWS * Hh;
  u16* WP1h = h2fl + (size_t)ROWS * Hh;            // 128*16*512
  u16* WP1l = WP1h + 128 * 16 * 512;
  u16* WP2h = WP1l + 128 * 16 * 512;               // 128*16*1024
  u16* WP2l = WP2h + 128 * 16 * 1024;
  u16* WoTh = WP2l + 128 * 16 * 1024;              // PC*Hh
  u16* WoTl = WoTh + PC * Hh;
  u16* Xhi  = WoTl + PC * Hh;                      // ROWS*Dd
  u16* Xlo  = Xhi  + (size_t)ROWS * Dd;
  u16* W1Th = Xlo  + (size_t)ROWS * Dd;            // Gg*Dd
  u16* W1Tl = W1Th + (size_t)Gg * Dd;
  const size_t need = (size_t)((char*)(W1Tl + (size_t)Gg * Dd) - (char*)d_ws);
  const bool use_mfma = ws_size >= need;

  // weights: permute+split once
  permuteW<<<dim3(16, 64), dim3(32, 8), 0, stream>>>(
      W1 + (size_t)Dd * Gg, WP1h, WP1l, 512);
  permuteW<<<dim3(32, 64), dim3(32, 8), 0, stream>>>(W2, WP2h, WP2l, 1024);
  convert_woutT<<<PC, 256, 0, stream>>>(Wout, WoTh, WoTl);

  // Layer 1 input projection: pre = X @ W1[0:D,:] + b1
  if (use_mfma) {
    convert_hilo<<<2048, 256, 0, stream>>>(inputs, Xhi, Xlo, ROWS * Dd / 4);
    convertT_w1<<<dim3(64, 64), dim3(32, 8), 0, stream>>>(W1, W1Th, W1Tl);
    gemm1_mfma<<<1024, 256, 0, stream>>>(Xhi, Xlo, W1Th, W1Tl, b1, pre);
  } else {
    sgemm_bias<<<dim3(Gg / BN, ROWS / BM), dim3(256), 0, stream>>>(
        inputs, W1, b1, pre, ROWS, Gg, Dd);
  }

  // Recurrence: phase t = L1 step t (blocks 0..511) + L2 step t-1 (512..1023)
  for (int t = 0; t <= Tt; ++t)
    fused_step4<<<1024, 256, 0, stream>>>(pre, WP1h, WP1l, WP2h, WP2l, b2,
                                          h1hi, h1lo, h2hi, h2lo,
                                          h2fh, h2fl, c1, c2, t);

  // Output projection with fused softmax/CE, then cost reduction
  gemm_proj<<<ROWS / 128, 256, 0, stream>>>(h2fh, h2fl, WoTh, WoTl, bout,
                                            labels, out, ceb);
  reduce_cost<<<1, 256, 0, stream>>>(ceb, out + (size_t)ROWS * Cc);
}